// Round 14
// baseline (711.235 us; speedup 1.0000x reference)
//
#include <hip/hip_runtime.h>

#define NROWS 65536
#define DDIM  256
#define KCODES 1024
#define MARGIN 0.05f        // bulk ambiguity threshold (>> split error + window)
#define TIE_WINDOW 8.0e-5   // proven r11/r12
#define FLAGCAP 8192

typedef __attribute__((ext_vector_type(8))) short bf16x8;
typedef __attribute__((ext_vector_type(4))) float f32x4;

union F4 { float4 v; float f[4]; };

__device__ __forceinline__ unsigned bf16rne(float f) {
    unsigned u = __float_as_uint(f);
    return (u + 0x7fffu + ((u >> 16) & 1u)) >> 16;
}
__device__ __forceinline__ float bf16tof(unsigned h) {
    return __uint_as_float(h << 16);
}

// ---- kernel 0: c2 f32 + f64, zero counter ----
__global__ __launch_bounds__(64) void c2_kernel(const float* __restrict__ cb,
                                                float* __restrict__ c2f,
                                                double* __restrict__ c2d,
                                                int* __restrict__ cnt) {
    const int c = blockIdx.x, lane = threadIdx.x;
    if (c == 0 && lane == 0) cnt[0] = 0;
    F4 v; v.v = reinterpret_cast<const float4*>(cb + (size_t)c * DDIM)[lane];
    double s = (double)v.f[0] * v.f[0] + (double)v.f[1] * v.f[1]
             + (double)v.f[2] * v.f[2] + (double)v.f[3] * v.f[3];
    #pragma unroll
    for (int off = 32; off; off >>= 1) s += __shfl_xor(s, off);
    if (lane == 0) { c2d[c] = s; c2f[c] = (float)s; }
}

// ---- kernel 1: codebook -> fragment-linear bf16 hi/lo (same as r13) ----
__global__ __launch_bounds__(256) void prep_frags(const float* __restrict__ cb,
                                                  unsigned short* __restrict__ fh,
                                                  unsigned short* __restrict__ fl) {
    int t = blockIdx.x * 256 + threadIdx.x;      // 0..65535
    int j0   = (t & 1) * 4;
    int lane = (t >> 1) & 63;
    int ks   = (t >> 7) & 7;
    int ntg  = t >> 10;
    int c = ntg * 16 + (lane & 15);
    int k = ks * 32 + (lane >> 4) * 8 + j0;
    F4 v; v.v = *reinterpret_cast<const float4*>(cb + (size_t)c * DDIM + k);
    unsigned h0 = bf16rne(v.f[0]), h1 = bf16rne(v.f[1]),
             h2 = bf16rne(v.f[2]), h3 = bf16rne(v.f[3]);
    unsigned l0 = bf16rne(v.f[0] - bf16tof(h0)), l1 = bf16rne(v.f[1] - bf16tof(h1)),
             l2 = bf16rne(v.f[2] - bf16tof(h2)), l3 = bf16rne(v.f[3] - bf16tof(h3));
    unsigned* ph = reinterpret_cast<unsigned*>(fh + (size_t)t * 4);
    unsigned* pl = reinterpret_cast<unsigned*>(fl + (size_t)t * 4);
    ph[0] = h0 | (h1 << 16); ph[1] = h2 | (h3 << 16);
    pl[0] = l0 | (l1 << 16); pl[1] = l2 | (l3 << 16);
}

// ---- kernel 2: MFMA bulk, 8 waves, 2rt x 4nt per wave (low VGPR) ----
__global__ __launch_bounds__(512, 4) void vqmfma(const float* __restrict__ x,
                                                 const unsigned short* __restrict__ fbh,
                                                 const unsigned short* __restrict__ fbl,
                                                 const float* __restrict__ c2f,
                                                 float* __restrict__ out_idx,
                                                 int* __restrict__ flaglist,
                                                 int* __restrict__ cnt) {
    __shared__ bf16x8 lds_ah[2048];    // [rt_g 4][ks 8][lane 64] -> 32 KB
    __shared__ bf16x8 lds_al[2048];    // 32 KB
    __shared__ float  lds_c2[KCODES];  // 4 KB
    __shared__ float  m_b1[256]; __shared__ float m_b2[256]; __shared__ int m_i1[256];

    const int tid  = threadIdx.x;
    const int w    = tid >> 6;          // 0..7
    const int lane = tid & 63;
    const int rh   = w & 1;             // row half (rows rh*32 .. +32)
    const int g    = w >> 1;            // code group (codes g*64 .. +64 per chunk)
    const int row0 = blockIdx.x * 64;

    #pragma unroll
    for (int q = 0; q < 2; q++) lds_c2[q * 512 + tid] = c2f[q * 512 + tid];

    // stage x tile -> hi/lo fragments in LDS (fragment-linear layout)
    {
        const float4* gx = reinterpret_cast<const float4*>(x + (size_t)row0 * DDIM);
        unsigned* pah = reinterpret_cast<unsigned*>(lds_ah);
        unsigned* pal = reinterpret_cast<unsigned*>(lds_al);
        #pragma unroll
        for (int jj = 0; jj < 8; jj++) {
            int flat4 = jj * 512 + tid;
            int r = flat4 >> 6;
            int k = (flat4 & 63) * 4;
            F4 v; v.v = gx[flat4];
            int rt = r >> 4, row = r & 15;
            int ks = k >> 5, gg = (k >> 3) & 3, j0 = k & 7;   // j0 in {0,4}
            int laneS = gg * 16 + row;
            int u32i = ((((rt * 8 + ks) * 64 + laneS) * 8 + j0) >> 1);
            unsigned h0 = bf16rne(v.f[0]), h1 = bf16rne(v.f[1]),
                     h2 = bf16rne(v.f[2]), h3 = bf16rne(v.f[3]);
            pah[u32i]     = h0 | (h1 << 16);
            pah[u32i + 1] = h2 | (h3 << 16);
            unsigned l0 = bf16rne(v.f[0] - bf16tof(h0)), l1 = bf16rne(v.f[1] - bf16tof(h1)),
                     l2 = bf16rne(v.f[2] - bf16tof(h2)), l3 = bf16rne(v.f[3] - bf16tof(h3));
            pal[u32i]     = l0 | (l1 << 16);
            pal[u32i + 1] = l2 | (l3 << 16);
        }
    }
    __syncthreads();

    float bestv[8], secv[8]; int besti[8];
    #pragma unroll
    for (int e = 0; e < 8; e++) { bestv[e] = 1e30f; secv[e] = 1e30f; besti[e] = 0; }

    const bf16x8* Bh = reinterpret_cast<const bf16x8*>(fbh);
    const bf16x8* Bl = reinterpret_cast<const bf16x8*>(fbl);

    for (int cc = 0; cc < KCODES; cc += 256) {
        f32x4 acc[2][4];
        #pragma unroll
        for (int rt = 0; rt < 2; rt++)
            #pragma unroll
            for (int nt = 0; nt < 4; nt++) acc[rt][nt] = (f32x4){0.f, 0.f, 0.f, 0.f};

        for (int ks = 0; ks < 8; ks++) {
            bf16x8 ah[2], al[2];
            #pragma unroll
            for (int rt = 0; rt < 2; rt++) {
                int slot = (((rh * 2 + rt) * 8 + ks) * 64) + lane;
                ah[rt] = lds_ah[slot]; al[rt] = lds_al[slot];
            }
            #pragma unroll
            for (int nt = 0; nt < 4; nt++) {
                int ntg = (cc >> 4) + g * 4 + nt;
                int bslot = (ntg * 8 + ks) * 64 + lane;
                bf16x8 bh = Bh[bslot], bl = Bl[bslot];
                #pragma unroll
                for (int rt = 0; rt < 2; rt++) {
                    acc[rt][nt] = __builtin_amdgcn_mfma_f32_16x16x32_bf16(ah[rt], bh, acc[rt][nt], 0, 0, 0);
                    acc[rt][nt] = __builtin_amdgcn_mfma_f32_16x16x32_bf16(ah[rt], bl, acc[rt][nt], 0, 0, 0);
                    acc[rt][nt] = __builtin_amdgcn_mfma_f32_16x16x32_bf16(al[rt], bh, acc[rt][nt], 0, 0, 0);
                }
            }
        }
        // top-2 update: C/D layout col=lane&15, row=(lane>>4)*4+reg
        #pragma unroll
        for (int nt = 0; nt < 4; nt++) {
            int c = cc + g * 64 + nt * 16 + (lane & 15);
            float c2v = lds_c2[c];
            #pragma unroll
            for (int rt = 0; rt < 2; rt++)
                #pragma unroll
                for (int reg = 0; reg < 4; reg++) {
                    float s = __fmaf_rn(-2.f, acc[rt][nt][reg], c2v);
                    int e = rt * 4 + reg;
                    if (s < bestv[e]) { secv[e] = bestv[e]; bestv[e] = s; besti[e] = c; }
                    else if (s < secv[e]) secv[e] = s;
                }
        }
    }

    // merge across the 16 lanes sharing a row
    #pragma unroll
    for (int e = 0; e < 8; e++) {
        float b1 = bestv[e]; int i1 = besti[e]; float b2 = secv[e];
        #pragma unroll
        for (int off = 8; off; off >>= 1) {
            float o1 = __shfl_xor(b1, off, 16);
            int   oi = __shfl_xor(i1, off, 16);
            float o2 = __shfl_xor(b2, off, 16);
            if (o1 < b1 || (o1 == b1 && oi < i1)) { b2 = fminf(b1, o2); b1 = o1; i1 = oi; }
            else                                  { b2 = fminf(o1, b2); }
        }
        if ((lane & 15) == 0) {
            int rt = e >> 2, reg = e & 3;
            int rib = rh * 32 + rt * 16 + (lane >> 4) * 4 + reg;  // row in block
            m_b1[g * 64 + rib] = b1; m_i1[g * 64 + rib] = i1; m_b2[g * 64 + rib] = b2;
        }
    }
    __syncthreads();

    // cross-group merge (4 disjoint code groups) + flag + idx
    if (tid < 64) {
        float b1 = m_b1[tid]; int i1 = m_i1[tid]; float b2 = m_b2[tid];
        #pragma unroll
        for (int gg = 1; gg < 4; gg++) {
            float o1 = m_b1[gg * 64 + tid]; int oi = m_i1[gg * 64 + tid];
            float o2 = m_b2[gg * 64 + tid];
            if (o1 < b1 || (o1 == b1 && oi < i1)) { b2 = fminf(b1, o2); b1 = o1; i1 = oi; }
            else                                  { b2 = fminf(o1, b2); }
        }
        out_idx[row0 + tid] = (float)i1;
        if (b2 - b1 < MARGIN) {
            int slot = atomicAdd(cnt, 1);
            if (slot < FLAGCAP) flaglist[slot] = row0 + tid;
        }
    }
}

// ---- kernel 3: exact-f64 window-argmin re-solve of flagged rows ----
__global__ __launch_bounds__(256) void refine_kernel(const float* __restrict__ x,
                                                     const float* __restrict__ cb,
                                                     const double* __restrict__ c2d,
                                                     const int* __restrict__ flaglist,
                                                     const int* __restrict__ cnt,
                                                     float* __restrict__ out_idx) {
    __shared__ double xs[DDIM];
    __shared__ double redd[256];
    __shared__ int    redi[256];
    const int tid = threadIdx.x;
    const int n = min(cnt[0], FLAGCAP);

    for (int fi = blockIdx.x; fi < n; fi += gridDim.x) {
        const int row = flaglist[fi];
        const double xv = (double)x[(size_t)row * DDIM + tid];
        xs[tid] = xv;
        redd[tid] = xv * xv;
        __syncthreads();
        for (int off = 128; off; off >>= 1) {
            if (tid < off) redd[tid] += redd[tid + off];
            __syncthreads();
        }
        const double x2 = redd[0];
        __syncthreads();

        double d2v[4];
        #pragma unroll
        for (int j = 0; j < 4; j++) {
            const int c = tid + 256 * j;
            const float* cp = cb + (size_t)c * DDIM;
            double dot = 0.0;
            for (int d = 0; d < DDIM; d += 4) {
                F4 cv; cv.v = *reinterpret_cast<const float4*>(cp + d);
                dot += xs[d+0]*(double)cv.f[0] + xs[d+1]*(double)cv.f[1]
                     + xs[d+2]*(double)cv.f[2] + xs[d+3]*(double)cv.f[3];
            }
            d2v[j] = x2 - 2.0 * dot + c2d[c];
        }
        double mv = fmin(fmin(d2v[0], d2v[1]), fmin(d2v[2], d2v[3]));
        redd[tid] = mv;
        __syncthreads();
        for (int off = 128; off; off >>= 1) {
            if (tid < off) redd[tid] = fmin(redd[tid], redd[tid + off]);
            __syncthreads();
        }
        const double thr = redd[0] + TIE_WINDOW;
        __syncthreads();
        int ci = 0x7fffffff;
        #pragma unroll
        for (int j = 0; j < 4; j++)
            if (d2v[j] <= thr) ci = min(ci, tid + 256 * j);
        redi[tid] = ci;
        __syncthreads();
        for (int off = 128; off; off >>= 1) {
            if (tid < off) redi[tid] = min(redi[tid], redi[tid + off]);
            __syncthreads();
        }
        if (tid == 0) out_idx[row] = (float)redi[0];
        __syncthreads();
    }
}

// ---- kernel 4: gather quantized + per-block squared-error partials ----
__global__ __launch_bounds__(256) void gather_kernel(const float* __restrict__ x,
                                                     const float* __restrict__ cb,
                                                     const float* __restrict__ out_idx,
                                                     float* __restrict__ out_q,
                                                     float* __restrict__ partial) {
    __shared__ float wsum[4];
    const int tid = threadIdx.x;
    const int row = blockIdx.x * 32 + (tid >> 3);
    const int d0  = (tid & 7) * 32;
    const int bi  = (int)out_idx[row];
    const float4* gq = reinterpret_cast<const float4*>(cb + (size_t)bi * DDIM + d0);
    const float4* gx = reinterpret_cast<const float4*>(x + (size_t)row * DDIM + d0);
    float4* go = reinterpret_cast<float4*>(out_q + (size_t)row * DDIM + d0);
    float sq = 0.f;
    #pragma unroll
    for (int j = 0; j < 8; j++) {
        F4 q, xv; q.v = gq[j]; xv.v = gx[j];
        go[j] = q.v;
        #pragma unroll
        for (int t = 0; t < 4; t++) { float d = q.f[t] - xv.f[t]; sq += d * d; }
    }
    #pragma unroll
    for (int off = 32; off; off >>= 1) sq += __shfl_down(sq, off);
    if ((tid & 63) == 0) wsum[tid >> 6] = sq;
    __syncthreads();
    if (tid == 0) partial[blockIdx.x] = wsum[0] + wsum[1] + wsum[2] + wsum[3];
}

// ---- kernel 5: loss reduction ----
__global__ __launch_bounds__(256) void loss_kernel(const float* __restrict__ partial,
                                                   float* __restrict__ out_loss) {
    __shared__ float w[4];
    float s = 0.f;
    for (int j = threadIdx.x; j < 2048; j += 256) s += partial[j];
    #pragma unroll
    for (int off = 32; off; off >>= 1) s += __shfl_down(s, off);
    if ((threadIdx.x & 63) == 0) w[threadIdx.x >> 6] = s;
    __syncthreads();
    if (threadIdx.x == 0)
        out_loss[0] = 1.25f * (w[0] + w[1] + w[2] + w[3]) / 16777216.f;
}

extern "C" void kernel_launch(void* const* d_in, const int* in_sizes, int n_in,
                              void* d_out, int out_size, void* d_ws, size_t ws_size,
                              hipStream_t stream) {
    const float* x  = (const float*)d_in[0];
    const float* cb = (const float*)d_in[1];
    float* out      = (float*)d_out;
    float* out_q    = out;                       // 16777216 floats
    float* out_loss = out + 16777216;            // 1 float
    float* out_idx  = out + 16777217;            // 65536 floats

    // codebook fragment buffers live in d_out's first 1 MB (gather rewrites it)
    unsigned short* fbh = (unsigned short*)d_out;            // 512 KB
    unsigned short* fbl = fbh + 262144;                      // 512 KB

    // workspace (~53 KB, proven-safe range)
    char* wsp = (char*)d_ws;
    float*  ws_c2f     = (float*) (wsp +     0);   //  4 KB
    double* ws_c2d     = (double*)(wsp +  4096);   //  8 KB
    float*  ws_partial = (float*) (wsp + 12288);   //  8 KB (2048 f32)
    int*    ws_flag    = (int*)   (wsp + 20480);   // 32 KB
    int*    ws_cnt     = (int*)   (wsp + 53248);   //  4 B

    c2_kernel<<<KCODES, 64, 0, stream>>>(cb, ws_c2f, ws_c2d, ws_cnt);
    prep_frags<<<256, 256, 0, stream>>>(cb, fbh, fbl);
    vqmfma<<<NROWS / 64, 512, 0, stream>>>(x, fbh, fbl, ws_c2f,
                                           out_idx, ws_flag, ws_cnt);
    refine_kernel<<<256, 256, 0, stream>>>(x, cb, ws_c2d, ws_flag, ws_cnt, out_idx);
    gather_kernel<<<NROWS / 32, 256, 0, stream>>>(x, cb, out_idx, out_q, ws_partial);
    loss_kernel<<<1, 256, 0, stream>>>(ws_partial, out_loss);
}

// Round 15
// 610.236 us; speedup vs baseline: 1.1655x; 1.1655x over previous
//
#include <hip/hip_runtime.h>

#define NROWS 65536
#define DDIM  256
#define KCODES 1024
#define MARGIN 0.05f        // bulk ambiguity threshold (>> split error + window)
#define TIE_WINDOW 8.0e-5   // proven r11/r12
#define FLAGCAP 8192

typedef __attribute__((ext_vector_type(8))) short bf16x8;
typedef __attribute__((ext_vector_type(4))) float f32x4;

union F4 { float4 v; float f[4]; };

__device__ __forceinline__ unsigned bf16rne(float f) {
    unsigned u = __float_as_uint(f);
    return (u + 0x7fffu + ((u >> 16) & 1u)) >> 16;
}
__device__ __forceinline__ float bf16tof(unsigned h) {
    return __uint_as_float(h << 16);
}

// ---- kernel 0: c2 f32 + f64, zero counter ----
__global__ __launch_bounds__(64) void c2_kernel(const float* __restrict__ cb,
                                                float* __restrict__ c2f,
                                                double* __restrict__ c2d,
                                                int* __restrict__ cnt) {
    const int c = blockIdx.x, lane = threadIdx.x;
    if (c == 0 && lane == 0) cnt[0] = 0;
    F4 v; v.v = reinterpret_cast<const float4*>(cb + (size_t)c * DDIM)[lane];
    double s = (double)v.f[0] * v.f[0] + (double)v.f[1] * v.f[1]
             + (double)v.f[2] * v.f[2] + (double)v.f[3] * v.f[3];
    #pragma unroll
    for (int off = 32; off; off >>= 1) s += __shfl_xor(s, off);
    if (lane == 0) { c2d[c] = s; c2f[c] = (float)s; }
}

// ---- kernel 1: codebook -> fragment-linear bf16 hi/lo ----
__global__ __launch_bounds__(256) void prep_frags(const float* __restrict__ cb,
                                                  unsigned short* __restrict__ fh,
                                                  unsigned short* __restrict__ fl) {
    int t = blockIdx.x * 256 + threadIdx.x;      // 0..65535
    int j0   = (t & 1) * 4;
    int lane = (t >> 1) & 63;
    int ks   = (t >> 7) & 7;
    int ntg  = t >> 10;
    int c = ntg * 16 + (lane & 15);
    int k = ks * 32 + (lane >> 4) * 8 + j0;
    F4 v; v.v = *reinterpret_cast<const float4*>(cb + (size_t)c * DDIM + k);
    unsigned h0 = bf16rne(v.f[0]), h1 = bf16rne(v.f[1]),
             h2 = bf16rne(v.f[2]), h3 = bf16rne(v.f[3]);
    unsigned l0 = bf16rne(v.f[0] - bf16tof(h0)), l1 = bf16rne(v.f[1] - bf16tof(h1)),
             l2 = bf16rne(v.f[2] - bf16tof(h2)), l3 = bf16rne(v.f[3] - bf16tof(h3));
    unsigned* ph = reinterpret_cast<unsigned*>(fh + (size_t)t * 4);
    unsigned* pl = reinterpret_cast<unsigned*>(fl + (size_t)t * 4);
    ph[0] = h0 | (h1 << 16); ph[1] = h2 | (h3 << 16);
    pl[0] = l0 | (l1 << 16); pl[1] = l2 | (l3 << 16);
}

// ---- kernel 2: MFMA bulk, 4 waves, 32 rows/block, 2rt x 4nt per wave ----
// VGPR demand ~110 incl. acc; cap 128 via launch_bounds(256,4) -> no spill.
__global__ __launch_bounds__(256, 4) void vqmfma(const float* __restrict__ x,
                                                 const unsigned short* __restrict__ fbh,
                                                 const unsigned short* __restrict__ fbl,
                                                 const float* __restrict__ c2f,
                                                 float* __restrict__ out_idx,
                                                 int* __restrict__ flaglist,
                                                 int* __restrict__ cnt) {
    __shared__ bf16x8 lds_ah[1024];    // [rt 2][ks 8][lane 64] -> 16 KB
    __shared__ bf16x8 lds_al[1024];    // 16 KB
    __shared__ float  lds_c2[KCODES];  // 4 KB
    __shared__ float  m_b1[128]; __shared__ float m_b2[128]; __shared__ int m_i1[128];

    const int tid  = threadIdx.x;
    const int w    = tid >> 6;          // 0..3 = code group g
    const int lane = tid & 63;
    const int row0 = blockIdx.x * 32;

    #pragma unroll
    for (int q = 0; q < 4; q++) lds_c2[q * 256 + tid] = c2f[q * 256 + tid];

    // stage x tile (32 rows) -> hi/lo fragments in LDS
    {
        const float4* gx = reinterpret_cast<const float4*>(x + (size_t)row0 * DDIM);
        unsigned* pah = reinterpret_cast<unsigned*>(lds_ah);
        unsigned* pal = reinterpret_cast<unsigned*>(lds_al);
        #pragma unroll
        for (int jj = 0; jj < 8; jj++) {
            int flat4 = jj * 256 + tid;
            int r = flat4 >> 6;                  // 0..31
            int k = (flat4 & 63) * 4;
            F4 v; v.v = gx[flat4];
            int rt = r >> 4, row = r & 15;
            int ks = k >> 5, gg = (k >> 3) & 3, j0 = k & 7;   // j0 in {0,4}
            int laneS = gg * 16 + row;
            int u32i = ((((rt * 8 + ks) * 64 + laneS) * 8 + j0) >> 1);
            unsigned h0 = bf16rne(v.f[0]), h1 = bf16rne(v.f[1]),
                     h2 = bf16rne(v.f[2]), h3 = bf16rne(v.f[3]);
            pah[u32i]     = h0 | (h1 << 16);
            pah[u32i + 1] = h2 | (h3 << 16);
            unsigned l0 = bf16rne(v.f[0] - bf16tof(h0)), l1 = bf16rne(v.f[1] - bf16tof(h1)),
                     l2 = bf16rne(v.f[2] - bf16tof(h2)), l3 = bf16rne(v.f[3] - bf16tof(h3));
            pal[u32i]     = l0 | (l1 << 16);
            pal[u32i + 1] = l2 | (l3 << 16);
        }
    }
    __syncthreads();

    float bestv[8], secv[8]; int besti[8];
    #pragma unroll
    for (int e = 0; e < 8; e++) { bestv[e] = 1e30f; secv[e] = 1e30f; besti[e] = 0; }

    const bf16x8* Bh = reinterpret_cast<const bf16x8*>(fbh);
    const bf16x8* Bl = reinterpret_cast<const bf16x8*>(fbl);

    for (int cc = 0; cc < KCODES; cc += 256) {
        f32x4 acc[2][4];
        #pragma unroll
        for (int rt = 0; rt < 2; rt++)
            #pragma unroll
            for (int nt = 0; nt < 4; nt++) acc[rt][nt] = (f32x4){0.f, 0.f, 0.f, 0.f};

        for (int ks = 0; ks < 8; ks++) {
            bf16x8 ah[2], al[2];
            #pragma unroll
            for (int rt = 0; rt < 2; rt++) {
                int slot = (rt * 8 + ks) * 64 + lane;
                ah[rt] = lds_ah[slot]; al[rt] = lds_al[slot];
            }
            #pragma unroll
            for (int nt = 0; nt < 4; nt++) {
                int ntg = (cc >> 4) + w * 4 + nt;
                int bslot = (ntg * 8 + ks) * 64 + lane;
                bf16x8 bh = Bh[bslot], bl = Bl[bslot];
                #pragma unroll
                for (int rt = 0; rt < 2; rt++) {
                    acc[rt][nt] = __builtin_amdgcn_mfma_f32_16x16x32_bf16(ah[rt], bh, acc[rt][nt], 0, 0, 0);
                    acc[rt][nt] = __builtin_amdgcn_mfma_f32_16x16x32_bf16(ah[rt], bl, acc[rt][nt], 0, 0, 0);
                    acc[rt][nt] = __builtin_amdgcn_mfma_f32_16x16x32_bf16(al[rt], bh, acc[rt][nt], 0, 0, 0);
                }
            }
        }
        // top-2 update: C/D layout col=lane&15, row=(lane>>4)*4+reg
        #pragma unroll
        for (int nt = 0; nt < 4; nt++) {
            int c = cc + w * 64 + nt * 16 + (lane & 15);
            float c2v = lds_c2[c];
            #pragma unroll
            for (int rt = 0; rt < 2; rt++)
                #pragma unroll
                for (int reg = 0; reg < 4; reg++) {
                    float s = __fmaf_rn(-2.f, acc[rt][nt][reg], c2v);
                    int e = rt * 4 + reg;
                    if (s < bestv[e]) { secv[e] = bestv[e]; bestv[e] = s; besti[e] = c; }
                    else if (s < secv[e]) secv[e] = s;
                }
        }
    }

    // merge across the 16 lanes sharing a row
    #pragma unroll
    for (int e = 0; e < 8; e++) {
        float b1 = bestv[e]; int i1 = besti[e]; float b2 = secv[e];
        #pragma unroll
        for (int off = 8; off; off >>= 1) {
            float o1 = __shfl_xor(b1, off, 16);
            int   oi = __shfl_xor(i1, off, 16);
            float o2 = __shfl_xor(b2, off, 16);
            if (o1 < b1 || (o1 == b1 && oi < i1)) { b2 = fminf(b1, o2); b1 = o1; i1 = oi; }
            else                                  { b2 = fminf(o1, b2); }
        }
        if ((lane & 15) == 0) {
            int rt = e >> 2, reg = e & 3;
            int rib = rt * 16 + (lane >> 4) * 4 + reg;  // row in block (0..31)
            m_b1[w * 32 + rib] = b1; m_i1[w * 32 + rib] = i1; m_b2[w * 32 + rib] = b2;
        }
    }
    __syncthreads();

    // cross-wave merge (4 disjoint code groups) + flag + idx
    if (tid < 32) {
        float b1 = m_b1[tid]; int i1 = m_i1[tid]; float b2 = m_b2[tid];
        #pragma unroll
        for (int ww = 1; ww < 4; ww++) {
            float o1 = m_b1[ww * 32 + tid]; int oi = m_i1[ww * 32 + tid];
            float o2 = m_b2[ww * 32 + tid];
            if (o1 < b1 || (o1 == b1 && oi < i1)) { b2 = fminf(b1, o2); b1 = o1; i1 = oi; }
            else                                  { b2 = fminf(o1, b2); }
        }
        out_idx[row0 + tid] = (float)i1;
        if (b2 - b1 < MARGIN) {
            int slot = atomicAdd(cnt, 1);
            if (slot < FLAGCAP) flaglist[slot] = row0 + tid;
        }
    }
}

// ---- kernel 3: exact-f64 window-argmin re-solve of flagged rows ----
__global__ __launch_bounds__(256) void refine_kernel(const float* __restrict__ x,
                                                     const float* __restrict__ cb,
                                                     const double* __restrict__ c2d,
                                                     const int* __restrict__ flaglist,
                                                     const int* __restrict__ cnt,
                                                     float* __restrict__ out_idx) {
    __shared__ double xs[DDIM];
    __shared__ double redd[256];
    __shared__ int    redi[256];
    const int tid = threadIdx.x;
    const int n = min(cnt[0], FLAGCAP);

    for (int fi = blockIdx.x; fi < n; fi += gridDim.x) {
        const int row = flaglist[fi];
        const double xv = (double)x[(size_t)row * DDIM + tid];
        xs[tid] = xv;
        redd[tid] = xv * xv;
        __syncthreads();
        for (int off = 128; off; off >>= 1) {
            if (tid < off) redd[tid] += redd[tid + off];
            __syncthreads();
        }
        const double x2 = redd[0];
        __syncthreads();

        double d2v[4];
        #pragma unroll
        for (int j = 0; j < 4; j++) {
            const int c = tid + 256 * j;
            const float* cp = cb + (size_t)c * DDIM;
            double dot = 0.0;
            for (int d = 0; d < DDIM; d += 4) {
                F4 cv; cv.v = *reinterpret_cast<const float4*>(cp + d);
                dot += xs[d+0]*(double)cv.f[0] + xs[d+1]*(double)cv.f[1]
                     + xs[d+2]*(double)cv.f[2] + xs[d+3]*(double)cv.f[3];
            }
            d2v[j] = x2 - 2.0 * dot + c2d[c];
        }
        double mv = fmin(fmin(d2v[0], d2v[1]), fmin(d2v[2], d2v[3]));
        redd[tid] = mv;
        __syncthreads();
        for (int off = 128; off; off >>= 1) {
            if (tid < off) redd[tid] = fmin(redd[tid], redd[tid + off]);
            __syncthreads();
        }
        const double thr = redd[0] + TIE_WINDOW;
        __syncthreads();
        int ci = 0x7fffffff;
        #pragma unroll
        for (int j = 0; j < 4; j++)
            if (d2v[j] <= thr) ci = min(ci, tid + 256 * j);
        redi[tid] = ci;
        __syncthreads();
        for (int off = 128; off; off >>= 1) {
            if (tid < off) redi[tid] = min(redi[tid], redi[tid + off]);
            __syncthreads();
        }
        if (tid == 0) out_idx[row] = (float)redi[0];
        __syncthreads();
    }
}

// ---- kernel 4: gather quantized + per-block squared-error partials ----
__global__ __launch_bounds__(256) void gather_kernel(const float* __restrict__ x,
                                                     const float* __restrict__ cb,
                                                     const float* __restrict__ out_idx,
                                                     float* __restrict__ out_q,
                                                     float* __restrict__ partial) {
    __shared__ float wsum[4];
    const int tid = threadIdx.x;
    const int row = blockIdx.x * 32 + (tid >> 3);
    const int d0  = (tid & 7) * 32;
    const int bi  = (int)out_idx[row];
    const float4* gq = reinterpret_cast<const float4*>(cb + (size_t)bi * DDIM + d0);
    const float4* gx = reinterpret_cast<const float4*>(x + (size_t)row * DDIM + d0);
    float4* go = reinterpret_cast<float4*>(out_q + (size_t)row * DDIM + d0);
    float sq = 0.f;
    #pragma unroll
    for (int j = 0; j < 8; j++) {
        F4 q, xv; q.v = gq[j]; xv.v = gx[j];
        go[j] = q.v;
        #pragma unroll
        for (int t = 0; t < 4; t++) { float d = q.f[t] - xv.f[t]; sq += d * d; }
    }
    #pragma unroll
    for (int off = 32; off; off >>= 1) sq += __shfl_down(sq, off);
    if ((tid & 63) == 0) wsum[tid >> 6] = sq;
    __syncthreads();
    if (tid == 0) partial[blockIdx.x] = wsum[0] + wsum[1] + wsum[2] + wsum[3];
}

// ---- kernel 5: loss reduction ----
__global__ __launch_bounds__(256) void loss_kernel(const float* __restrict__ partial,
                                                   float* __restrict__ out_loss) {
    __shared__ float w[4];
    float s = 0.f;
    for (int j = threadIdx.x; j < 2048; j += 256) s += partial[j];
    #pragma unroll
    for (int off = 32; off; off >>= 1) s += __shfl_down(s, off);
    if ((threadIdx.x & 63) == 0) w[threadIdx.x >> 6] = s;
    __syncthreads();
    if (threadIdx.x == 0)
        out_loss[0] = 1.25f * (w[0] + w[1] + w[2] + w[3]) / 16777216.f;
}

extern "C" void kernel_launch(void* const* d_in, const int* in_sizes, int n_in,
                              void* d_out, int out_size, void* d_ws, size_t ws_size,
                              hipStream_t stream) {
    const float* x  = (const float*)d_in[0];
    const float* cb = (const float*)d_in[1];
    float* out      = (float*)d_out;
    float* out_q    = out;                       // 16777216 floats
    float* out_loss = out + 16777216;            // 1 float
    float* out_idx  = out + 16777217;            // 65536 floats

    // codebook fragment buffers live in d_out's first 1 MB (gather rewrites it)
    unsigned short* fbh = (unsigned short*)d_out;            // 512 KB
    unsigned short* fbl = fbh + 262144;                      // 512 KB

    // workspace (~53 KB, proven-safe range)
    char* wsp = (char*)d_ws;
    float*  ws_c2f     = (float*) (wsp +     0);   //  4 KB
    double* ws_c2d     = (double*)(wsp +  4096);   //  8 KB
    float*  ws_partial = (float*) (wsp + 12288);   //  8 KB (2048 f32)
    int*    ws_flag    = (int*)   (wsp + 20480);   // 32 KB
    int*    ws_cnt     = (int*)   (wsp + 53248);   //  4 B

    c2_kernel<<<KCODES, 64, 0, stream>>>(cb, ws_c2f, ws_c2d, ws_cnt);
    prep_frags<<<256, 256, 0, stream>>>(cb, fbh, fbl);
    vqmfma<<<NROWS / 32, 256, 0, stream>>>(x, fbh, fbl, ws_c2f,
                                           out_idx, ws_flag, ws_cnt);
    refine_kernel<<<256, 256, 0, stream>>>(x, cb, ws_c2d, ws_flag, ws_cnt, out_idx);
    gather_kernel<<<NROWS / 32, 256, 0, stream>>>(x, cb, out_idx, out_q, ws_partial);
    loss_kernel<<<1, 256, 0, stream>>>(ws_partial, out_loss);
}

// Round 16
// 541.203 us; speedup vs baseline: 1.3142x; 1.1276x over previous
//
#include <hip/hip_runtime.h>

#define NROWS 65536
#define DDIM  256
#define KCODES 1024
#define MARGIN 0.05f        // bulk ambiguity threshold (>> split error + window)
#define TIE_WINDOW 8.0e-5   // proven r11/r12
#define FLAGCAP 8192

typedef __attribute__((ext_vector_type(8))) short bf16x8;
typedef __attribute__((ext_vector_type(4))) float f32x4;

union F4 { float4 v; float f[4]; };

__device__ __forceinline__ unsigned bf16rne(float f) {
    unsigned u = __float_as_uint(f);
    return (u + 0x7fffu + ((u >> 16) & 1u)) >> 16;
}
__device__ __forceinline__ float bf16tof(unsigned h) {
    return __uint_as_float(h << 16);
}

// ---- kernel 0: c2 f32 + f64, zero counter ----
__global__ __launch_bounds__(64) void c2_kernel(const float* __restrict__ cb,
                                                float* __restrict__ c2f,
                                                double* __restrict__ c2d,
                                                int* __restrict__ cnt) {
    const int c = blockIdx.x, lane = threadIdx.x;
    if (c == 0 && lane == 0) cnt[0] = 0;
    F4 v; v.v = reinterpret_cast<const float4*>(cb + (size_t)c * DDIM)[lane];
    double s = (double)v.f[0] * v.f[0] + (double)v.f[1] * v.f[1]
             + (double)v.f[2] * v.f[2] + (double)v.f[3] * v.f[3];
    #pragma unroll
    for (int off = 32; off; off >>= 1) s += __shfl_xor(s, off);
    if (lane == 0) { c2d[c] = s; c2f[c] = (float)s; }
}

// ---- kernel 1: codebook -> fragment-linear bf16 hi/lo ----
__global__ __launch_bounds__(256) void prep_frags(const float* __restrict__ cb,
                                                  unsigned short* __restrict__ fh,
                                                  unsigned short* __restrict__ fl) {
    int t = blockIdx.x * 256 + threadIdx.x;      // 0..65535
    int j0   = (t & 1) * 4;
    int lane = (t >> 1) & 63;
    int ks   = (t >> 7) & 7;
    int ntg  = t >> 10;
    int c = ntg * 16 + (lane & 15);
    int k = ks * 32 + (lane >> 4) * 8 + j0;
    F4 v; v.v = *reinterpret_cast<const float4*>(cb + (size_t)c * DDIM + k);
    unsigned h0 = bf16rne(v.f[0]), h1 = bf16rne(v.f[1]),
             h2 = bf16rne(v.f[2]), h3 = bf16rne(v.f[3]);
    unsigned l0 = bf16rne(v.f[0] - bf16tof(h0)), l1 = bf16rne(v.f[1] - bf16tof(h1)),
             l2 = bf16rne(v.f[2] - bf16tof(h2)), l3 = bf16rne(v.f[3] - bf16tof(h3));
    unsigned* ph = reinterpret_cast<unsigned*>(fh + (size_t)t * 4);
    unsigned* pl = reinterpret_cast<unsigned*>(fl + (size_t)t * 4);
    ph[0] = h0 | (h1 << 16); ph[1] = h2 | (h3 << 16);
    pl[0] = l0 | (l1 << 16); pl[1] = l2 | (l3 << 16);
}

// ---- kernel 2: MFMA bulk, 4 waves, 32 rows/block, 2rt x 4nt per wave ----
// launch_bounds(256,2): cap 256 VGPR, allocator takes natural ~110-130.
// (r14/r15 lesson: min-waves=4 clamped VGPR to 64 -> 490 MB scratch spill.)
__global__ __launch_bounds__(256, 2) void vqmfma(const float* __restrict__ x,
                                                 const unsigned short* __restrict__ fbh,
                                                 const unsigned short* __restrict__ fbl,
                                                 const float* __restrict__ c2f,
                                                 float* __restrict__ out_idx,
                                                 int* __restrict__ flaglist,
                                                 int* __restrict__ cnt) {
    __shared__ bf16x8 lds_ah[1024];    // [rt 2][ks 8][lane 64] -> 16 KB
    __shared__ bf16x8 lds_al[1024];    // 16 KB
    __shared__ float  lds_c2[KCODES];  // 4 KB
    __shared__ float  m_b1[128]; __shared__ float m_b2[128]; __shared__ int m_i1[128];

    const int tid  = threadIdx.x;
    const int w    = tid >> 6;          // 0..3 = code group g
    const int lane = tid & 63;
    const int row0 = blockIdx.x * 32;

    #pragma unroll
    for (int q = 0; q < 4; q++) lds_c2[q * 256 + tid] = c2f[q * 256 + tid];

    // stage x tile (32 rows) -> hi/lo fragments in LDS
    {
        const float4* gx = reinterpret_cast<const float4*>(x + (size_t)row0 * DDIM);
        unsigned* pah = reinterpret_cast<unsigned*>(lds_ah);
        unsigned* pal = reinterpret_cast<unsigned*>(lds_al);
        #pragma unroll
        for (int jj = 0; jj < 8; jj++) {
            int flat4 = jj * 256 + tid;
            int r = flat4 >> 6;                  // 0..31
            int k = (flat4 & 63) * 4;
            F4 v; v.v = gx[flat4];
            int rt = r >> 4, row = r & 15;
            int ks = k >> 5, gg = (k >> 3) & 3, j0 = k & 7;   // j0 in {0,4}
            int laneS = gg * 16 + row;
            int u32i = ((((rt * 8 + ks) * 64 + laneS) * 8 + j0) >> 1);
            unsigned h0 = bf16rne(v.f[0]), h1 = bf16rne(v.f[1]),
                     h2 = bf16rne(v.f[2]), h3 = bf16rne(v.f[3]);
            pah[u32i]     = h0 | (h1 << 16);
            pah[u32i + 1] = h2 | (h3 << 16);
            unsigned l0 = bf16rne(v.f[0] - bf16tof(h0)), l1 = bf16rne(v.f[1] - bf16tof(h1)),
                     l2 = bf16rne(v.f[2] - bf16tof(h2)), l3 = bf16rne(v.f[3] - bf16tof(h3));
            pal[u32i]     = l0 | (l1 << 16);
            pal[u32i + 1] = l2 | (l3 << 16);
        }
    }
    __syncthreads();

    float bestv[8], secv[8]; int besti[8];
    #pragma unroll
    for (int e = 0; e < 8; e++) { bestv[e] = 1e30f; secv[e] = 1e30f; besti[e] = 0; }

    const bf16x8* Bh = reinterpret_cast<const bf16x8*>(fbh);
    const bf16x8* Bl = reinterpret_cast<const bf16x8*>(fbl);

    for (int cc = 0; cc < KCODES; cc += 256) {
        f32x4 acc[2][4];
        #pragma unroll
        for (int rt = 0; rt < 2; rt++)
            #pragma unroll
            for (int nt = 0; nt < 4; nt++) acc[rt][nt] = (f32x4){0.f, 0.f, 0.f, 0.f};

        for (int ks = 0; ks < 8; ks++) {
            bf16x8 ah[2], al[2];
            #pragma unroll
            for (int rt = 0; rt < 2; rt++) {
                int slot = (rt * 8 + ks) * 64 + lane;
                ah[rt] = lds_ah[slot]; al[rt] = lds_al[slot];
            }
            #pragma unroll
            for (int nt = 0; nt < 4; nt++) {
                int ntg = (cc >> 4) + w * 4 + nt;
                int bslot = (ntg * 8 + ks) * 64 + lane;
                bf16x8 bh = Bh[bslot], bl = Bl[bslot];
                #pragma unroll
                for (int rt = 0; rt < 2; rt++) {
                    acc[rt][nt] = __builtin_amdgcn_mfma_f32_16x16x32_bf16(ah[rt], bh, acc[rt][nt], 0, 0, 0);
                    acc[rt][nt] = __builtin_amdgcn_mfma_f32_16x16x32_bf16(ah[rt], bl, acc[rt][nt], 0, 0, 0);
                    acc[rt][nt] = __builtin_amdgcn_mfma_f32_16x16x32_bf16(al[rt], bh, acc[rt][nt], 0, 0, 0);
                }
            }
        }
        // top-2 update: C/D layout col=lane&15, row=(lane>>4)*4+reg
        #pragma unroll
        for (int nt = 0; nt < 4; nt++) {
            int c = cc + w * 64 + nt * 16 + (lane & 15);
            float c2v = lds_c2[c];
            #pragma unroll
            for (int rt = 0; rt < 2; rt++)
                #pragma unroll
                for (int reg = 0; reg < 4; reg++) {
                    float s = __fmaf_rn(-2.f, acc[rt][nt][reg], c2v);
                    int e = rt * 4 + reg;
                    if (s < bestv[e]) { secv[e] = bestv[e]; bestv[e] = s; besti[e] = c; }
                    else if (s < secv[e]) secv[e] = s;
                }
        }
    }

    // merge across the 16 lanes sharing a row
    #pragma unroll
    for (int e = 0; e < 8; e++) {
        float b1 = bestv[e]; int i1 = besti[e]; float b2 = secv[e];
        #pragma unroll
        for (int off = 8; off; off >>= 1) {
            float o1 = __shfl_xor(b1, off, 16);
            int   oi = __shfl_xor(i1, off, 16);
            float o2 = __shfl_xor(b2, off, 16);
            if (o1 < b1 || (o1 == b1 && oi < i1)) { b2 = fminf(b1, o2); b1 = o1; i1 = oi; }
            else                                  { b2 = fminf(o1, b2); }
        }
        if ((lane & 15) == 0) {
            int rt = e >> 2, reg = e & 3;
            int rib = rt * 16 + (lane >> 4) * 4 + reg;  // row in block (0..31)
            m_b1[w * 32 + rib] = b1; m_i1[w * 32 + rib] = i1; m_b2[w * 32 + rib] = b2;
        }
    }
    __syncthreads();

    // cross-wave merge (4 disjoint code groups) + flag + idx
    if (tid < 32) {
        float b1 = m_b1[tid]; int i1 = m_i1[tid]; float b2 = m_b2[tid];
        #pragma unroll
        for (int ww = 1; ww < 4; ww++) {
            float o1 = m_b1[ww * 32 + tid]; int oi = m_i1[ww * 32 + tid];
            float o2 = m_b2[ww * 32 + tid];
            if (o1 < b1 || (o1 == b1 && oi < i1)) { b2 = fminf(b1, o2); b1 = o1; i1 = oi; }
            else                                  { b2 = fminf(o1, b2); }
        }
        out_idx[row0 + tid] = (float)i1;
        if (b2 - b1 < MARGIN) {
            int slot = atomicAdd(cnt, 1);
            if (slot < FLAGCAP) flaglist[slot] = row0 + tid;
        }
    }
}

// ---- kernel 3: exact-f64 window-argmin re-solve of flagged rows ----
__global__ __launch_bounds__(256) void refine_kernel(const float* __restrict__ x,
                                                     const float* __restrict__ cb,
                                                     const double* __restrict__ c2d,
                                                     const int* __restrict__ flaglist,
                                                     const int* __restrict__ cnt,
                                                     float* __restrict__ out_idx) {
    __shared__ double xs[DDIM];
    __shared__ double redd[256];
    __shared__ int    redi[256];
    const int tid = threadIdx.x;
    const int n = min(cnt[0], FLAGCAP);

    for (int fi = blockIdx.x; fi < n; fi += gridDim.x) {
        const int row = flaglist[fi];
        const double xv = (double)x[(size_t)row * DDIM + tid];
        xs[tid] = xv;
        redd[tid] = xv * xv;
        __syncthreads();
        for (int off = 128; off; off >>= 1) {
            if (tid < off) redd[tid] += redd[tid + off];
            __syncthreads();
        }
        const double x2 = redd[0];
        __syncthreads();

        double d2v[4];
        #pragma unroll
        for (int j = 0; j < 4; j++) {
            const int c = tid + 256 * j;
            const float* cp = cb + (size_t)c * DDIM;
            double dot = 0.0;
            for (int d = 0; d < DDIM; d += 4) {
                F4 cv; cv.v = *reinterpret_cast<const float4*>(cp + d);
                dot += xs[d+0]*(double)cv.f[0] + xs[d+1]*(double)cv.f[1]
                     + xs[d+2]*(double)cv.f[2] + xs[d+3]*(double)cv.f[3];
            }
            d2v[j] = x2 - 2.0 * dot + c2d[c];
        }
        double mv = fmin(fmin(d2v[0], d2v[1]), fmin(d2v[2], d2v[3]));
        redd[tid] = mv;
        __syncthreads();
        for (int off = 128; off; off >>= 1) {
            if (tid < off) redd[tid] = fmin(redd[tid], redd[tid + off]);
            __syncthreads();
        }
        const double thr = redd[0] + TIE_WINDOW;
        __syncthreads();
        int ci = 0x7fffffff;
        #pragma unroll
        for (int j = 0; j < 4; j++)
            if (d2v[j] <= thr) ci = min(ci, tid + 256 * j);
        redi[tid] = ci;
        __syncthreads();
        for (int off = 128; off; off >>= 1) {
            if (tid < off) redi[tid] = min(redi[tid], redi[tid + off]);
            __syncthreads();
        }
        if (tid == 0) out_idx[row] = (float)redi[0];
        __syncthreads();
    }
}

// ---- kernel 4: gather quantized + per-block squared-error partials ----
__global__ __launch_bounds__(256) void gather_kernel(const float* __restrict__ x,
                                                     const float* __restrict__ cb,
                                                     const float* __restrict__ out_idx,
                                                     float* __restrict__ out_q,
                                                     float* __restrict__ partial) {
    __shared__ float wsum[4];
    const int tid = threadIdx.x;
    const int row = blockIdx.x * 32 + (tid >> 3);
    const int d0  = (tid & 7) * 32;
    const int bi  = (int)out_idx[row];
    const float4* gq = reinterpret_cast<const float4*>(cb + (size_t)bi * DDIM + d0);
    const float4* gx = reinterpret_cast<const float4*>(x + (size_t)row * DDIM + d0);
    float4* go = reinterpret_cast<float4*>(out_q + (size_t)row * DDIM + d0);
    float sq = 0.f;
    #pragma unroll
    for (int j = 0; j < 8; j++) {
        F4 q, xv; q.v = gq[j]; xv.v = gx[j];
        go[j] = q.v;
        #pragma unroll
        for (int t = 0; t < 4; t++) { float d = q.f[t] - xv.f[t]; sq += d * d; }
    }
    #pragma unroll
    for (int off = 32; off; off >>= 1) sq += __shfl_down(sq, off);
    if ((tid & 63) == 0) wsum[tid >> 6] = sq;
    __syncthreads();
    if (tid == 0) partial[blockIdx.x] = wsum[0] + wsum[1] + wsum[2] + wsum[3];
}

// ---- kernel 5: loss reduction ----
__global__ __launch_bounds__(256) void loss_kernel(const float* __restrict__ partial,
                                                   float* __restrict__ out_loss) {
    __shared__ float w[4];
    float s = 0.f;
    for (int j = threadIdx.x; j < 2048; j += 256) s += partial[j];
    #pragma unroll
    for (int off = 32; off; off >>= 1) s += __shfl_down(s, off);
    if ((threadIdx.x & 63) == 0) w[threadIdx.x >> 6] = s;
    __syncthreads();
    if (threadIdx.x == 0)
        out_loss[0] = 1.25f * (w[0] + w[1] + w[2] + w[3]) / 16777216.f;
}

extern "C" void kernel_launch(void* const* d_in, const int* in_sizes, int n_in,
                              void* d_out, int out_size, void* d_ws, size_t ws_size,
                              hipStream_t stream) {
    const float* x  = (const float*)d_in[0];
    const float* cb = (const float*)d_in[1];
    float* out      = (float*)d_out;
    float* out_q    = out;                       // 16777216 floats
    float* out_loss = out + 16777216;            // 1 float
    float* out_idx  = out + 16777217;            // 65536 floats

    // codebook fragment buffers live in d_out's first 1 MB (gather rewrites it)
    unsigned short* fbh = (unsigned short*)d_out;            // 512 KB
    unsigned short* fbl = fbh + 262144;                      // 512 KB

    // workspace (~53 KB, proven-safe range)
    char* wsp = (char*)d_ws;
    float*  ws_c2f     = (float*) (wsp +     0);   //  4 KB
    double* ws_c2d     = (double*)(wsp +  4096);   //  8 KB
    float*  ws_partial = (float*) (wsp + 12288);   //  8 KB (2048 f32)
    int*    ws_flag    = (int*)   (wsp + 20480);   // 32 KB
    int*    ws_cnt     = (int*)   (wsp + 53248);   //  4 B

    c2_kernel<<<KCODES, 64, 0, stream>>>(cb, ws_c2f, ws_c2d, ws_cnt);
    prep_frags<<<256, 256, 0, stream>>>(cb, fbh, fbl);
    vqmfma<<<NROWS / 32, 256, 0, stream>>>(x, fbh, fbl, ws_c2f,
                                           out_idx, ws_flag, ws_cnt);
    refine_kernel<<<256, 256, 0, stream>>>(x, cb, ws_c2d, ws_flag, ws_cnt, out_idx);
    gather_kernel<<<NROWS / 32, 256, 0, stream>>>(x, cb, out_idx, out_q, ws_partial);
    loss_kernel<<<1, 256, 0, stream>>>(ws_partial, out_loss);
}

// Round 17
// 433.491 us; speedup vs baseline: 1.6407x; 1.2485x over previous
//
#include <hip/hip_runtime.h>

#define NROWS 65536
#define DDIM  256
#define KCODES 1024
#define MARGIN 0.05f        // bulk ambiguity threshold (>> split error + window)
#define TIE_WINDOW 8.0e-5   // proven r11/r12
#define FLAGCAP 8192

typedef __attribute__((ext_vector_type(8))) short bf16x8;
typedef __attribute__((ext_vector_type(4))) float f32x4;

union F4 { float4 v; float f[4]; };

__device__ __forceinline__ unsigned bf16rne(float f) {
    unsigned u = __float_as_uint(f);
    return (u + 0x7fffu + ((u >> 16) & 1u)) >> 16;
}
__device__ __forceinline__ float bf16tof(unsigned h) {
    return __uint_as_float(h << 16);
}

// ---- kernel 0: c2 f32 + f64, zero counter ----
__global__ __launch_bounds__(64) void c2_kernel(const float* __restrict__ cb,
                                                float* __restrict__ c2f,
                                                double* __restrict__ c2d,
                                                int* __restrict__ cnt) {
    const int c = blockIdx.x, lane = threadIdx.x;
    if (c == 0 && lane == 0) cnt[0] = 0;
    F4 v; v.v = reinterpret_cast<const float4*>(cb + (size_t)c * DDIM)[lane];
    double s = (double)v.f[0] * v.f[0] + (double)v.f[1] * v.f[1]
             + (double)v.f[2] * v.f[2] + (double)v.f[3] * v.f[3];
    #pragma unroll
    for (int off = 32; off; off >>= 1) s += __shfl_xor(s, off);
    if (lane == 0) { c2d[c] = s; c2f[c] = (float)s; }
}

// ---- kernel 1: codebook -> fragment-linear bf16 hi/lo ----
__global__ __launch_bounds__(256) void prep_frags(const float* __restrict__ cb,
                                                  unsigned short* __restrict__ fh,
                                                  unsigned short* __restrict__ fl) {
    int t = blockIdx.x * 256 + threadIdx.x;      // 0..65535
    int j0   = (t & 1) * 4;
    int lane = (t >> 1) & 63;
    int ks   = (t >> 7) & 7;
    int ntg  = t >> 10;
    int c = ntg * 16 + (lane & 15);
    int k = ks * 32 + (lane >> 4) * 8 + j0;
    F4 v; v.v = *reinterpret_cast<const float4*>(cb + (size_t)c * DDIM + k);
    unsigned h0 = bf16rne(v.f[0]), h1 = bf16rne(v.f[1]),
             h2 = bf16rne(v.f[2]), h3 = bf16rne(v.f[3]);
    unsigned l0 = bf16rne(v.f[0] - bf16tof(h0)), l1 = bf16rne(v.f[1] - bf16tof(h1)),
             l2 = bf16rne(v.f[2] - bf16tof(h2)), l3 = bf16rne(v.f[3] - bf16tof(h3));
    unsigned* ph = reinterpret_cast<unsigned*>(fh + (size_t)t * 4);
    unsigned* pl = reinterpret_cast<unsigned*>(fl + (size_t)t * 4);
    ph[0] = h0 | (h1 << 16); ph[1] = h2 | (h3 << 16);
    pl[0] = l0 | (l1 << 16); pl[1] = l2 | (l3 << 16);
}

// ---- kernel 2: MFMA bulk, 4 waves, 32 rows/block, 2rt x 4nt per wave ----
// __launch_bounds__(256) ONLY: natural VGPR (~150 demand) -> no spill.
// r13: unconstrained+bigger tile -> 256 VGPR, 1 blk/CU, latency-bound.
// r14/r15: min-waves=4 -> 64 VGPR, 490 MB spill. r16: min-waves=2 -> 128,
// 184 MB spill. Law: never cap below demand; demand here ~150.
__global__ __launch_bounds__(256) void vqmfma(const float* __restrict__ x,
                                              const unsigned short* __restrict__ fbh,
                                              const unsigned short* __restrict__ fbl,
                                              const float* __restrict__ c2f,
                                              float* __restrict__ out_idx,
                                              int* __restrict__ flaglist,
                                              int* __restrict__ cnt) {
    __shared__ bf16x8 lds_ah[1024];    // [rt 2][ks 8][lane 64] -> 16 KB
    __shared__ bf16x8 lds_al[1024];    // 16 KB
    __shared__ float  lds_c2[KCODES];  // 4 KB
    __shared__ float  m_b1[128]; __shared__ float m_b2[128]; __shared__ int m_i1[128];

    const int tid  = threadIdx.x;
    const int w    = tid >> 6;          // 0..3 = code group g
    const int lane = tid & 63;
    const int row0 = blockIdx.x * 32;

    #pragma unroll
    for (int q = 0; q < 4; q++) lds_c2[q * 256 + tid] = c2f[q * 256 + tid];

    // stage x tile (32 rows) -> hi/lo fragments in LDS
    {
        const float4* gx = reinterpret_cast<const float4*>(x + (size_t)row0 * DDIM);
        unsigned* pah = reinterpret_cast<unsigned*>(lds_ah);
        unsigned* pal = reinterpret_cast<unsigned*>(lds_al);
        #pragma unroll
        for (int jj = 0; jj < 8; jj++) {
            int flat4 = jj * 256 + tid;
            int r = flat4 >> 6;                  // 0..31
            int k = (flat4 & 63) * 4;
            F4 v; v.v = gx[flat4];
            int rt = r >> 4, row = r & 15;
            int ks = k >> 5, gg = (k >> 3) & 3, j0 = k & 7;   // j0 in {0,4}
            int laneS = gg * 16 + row;
            int u32i = ((((rt * 8 + ks) * 64 + laneS) * 8 + j0) >> 1);
            unsigned h0 = bf16rne(v.f[0]), h1 = bf16rne(v.f[1]),
                     h2 = bf16rne(v.f[2]), h3 = bf16rne(v.f[3]);
            pah[u32i]     = h0 | (h1 << 16);
            pah[u32i + 1] = h2 | (h3 << 16);
            unsigned l0 = bf16rne(v.f[0] - bf16tof(h0)), l1 = bf16rne(v.f[1] - bf16tof(h1)),
                     l2 = bf16rne(v.f[2] - bf16tof(h2)), l3 = bf16rne(v.f[3] - bf16tof(h3));
            pal[u32i]     = l0 | (l1 << 16);
            pal[u32i + 1] = l2 | (l3 << 16);
        }
    }
    __syncthreads();

    float bestv[8], secv[8]; int besti[8];
    #pragma unroll
    for (int e = 0; e < 8; e++) { bestv[e] = 1e30f; secv[e] = 1e30f; besti[e] = 0; }

    const bf16x8* Bh = reinterpret_cast<const bf16x8*>(fbh);
    const bf16x8* Bl = reinterpret_cast<const bf16x8*>(fbl);

    for (int cc = 0; cc < KCODES; cc += 256) {
        f32x4 acc[2][4];
        #pragma unroll
        for (int rt = 0; rt < 2; rt++)
            #pragma unroll
            for (int nt = 0; nt < 4; nt++) acc[rt][nt] = (f32x4){0.f, 0.f, 0.f, 0.f};

        for (int ks = 0; ks < 8; ks++) {
            bf16x8 ah[2], al[2];
            #pragma unroll
            for (int rt = 0; rt < 2; rt++) {
                int slot = (rt * 8 + ks) * 64 + lane;
                ah[rt] = lds_ah[slot]; al[rt] = lds_al[slot];
            }
            #pragma unroll
            for (int nt = 0; nt < 4; nt++) {
                int ntg = (cc >> 4) + w * 4 + nt;
                int bslot = (ntg * 8 + ks) * 64 + lane;
                bf16x8 bh = Bh[bslot], bl = Bl[bslot];
                #pragma unroll
                for (int rt = 0; rt < 2; rt++) {
                    acc[rt][nt] = __builtin_amdgcn_mfma_f32_16x16x32_bf16(ah[rt], bh, acc[rt][nt], 0, 0, 0);
                    acc[rt][nt] = __builtin_amdgcn_mfma_f32_16x16x32_bf16(ah[rt], bl, acc[rt][nt], 0, 0, 0);
                    acc[rt][nt] = __builtin_amdgcn_mfma_f32_16x16x32_bf16(al[rt], bh, acc[rt][nt], 0, 0, 0);
                }
            }
        }
        // top-2 update: C/D layout col=lane&15, row=(lane>>4)*4+reg
        #pragma unroll
        for (int nt = 0; nt < 4; nt++) {
            int c = cc + w * 64 + nt * 16 + (lane & 15);
            float c2v = lds_c2[c];
            #pragma unroll
            for (int rt = 0; rt < 2; rt++)
                #pragma unroll
                for (int reg = 0; reg < 4; reg++) {
                    float s = __fmaf_rn(-2.f, acc[rt][nt][reg], c2v);
                    int e = rt * 4 + reg;
                    if (s < bestv[e]) { secv[e] = bestv[e]; bestv[e] = s; besti[e] = c; }
                    else if (s < secv[e]) secv[e] = s;
                }
        }
    }

    // merge across the 16 lanes sharing a row
    #pragma unroll
    for (int e = 0; e < 8; e++) {
        float b1 = bestv[e]; int i1 = besti[e]; float b2 = secv[e];
        #pragma unroll
        for (int off = 8; off; off >>= 1) {
            float o1 = __shfl_xor(b1, off, 16);
            int   oi = __shfl_xor(i1, off, 16);
            float o2 = __shfl_xor(b2, off, 16);
            if (o1 < b1 || (o1 == b1 && oi < i1)) { b2 = fminf(b1, o2); b1 = o1; i1 = oi; }
            else                                  { b2 = fminf(o1, b2); }
        }
        if ((lane & 15) == 0) {
            int rt = e >> 2, reg = e & 3;
            int rib = rt * 16 + (lane >> 4) * 4 + reg;  // row in block (0..31)
            m_b1[w * 32 + rib] = b1; m_i1[w * 32 + rib] = i1; m_b2[w * 32 + rib] = b2;
        }
    }
    __syncthreads();

    // cross-wave merge (4 disjoint code groups) + flag + idx
    if (tid < 32) {
        float b1 = m_b1[tid]; int i1 = m_i1[tid]; float b2 = m_b2[tid];
        #pragma unroll
        for (int ww = 1; ww < 4; ww++) {
            float o1 = m_b1[ww * 32 + tid]; int oi = m_i1[ww * 32 + tid];
            float o2 = m_b2[ww * 32 + tid];
            if (o1 < b1 || (o1 == b1 && oi < i1)) { b2 = fminf(b1, o2); b1 = o1; i1 = oi; }
            else                                  { b2 = fminf(o1, b2); }
        }
        out_idx[row0 + tid] = (float)i1;
        if (b2 - b1 < MARGIN) {
            int slot = atomicAdd(cnt, 1);
            if (slot < FLAGCAP) flaglist[slot] = row0 + tid;
        }
    }
}

// ---- kernel 3: exact-f64 window-argmin re-solve of flagged rows ----
__global__ __launch_bounds__(256) void refine_kernel(const float* __restrict__ x,
                                                     const float* __restrict__ cb,
                                                     const double* __restrict__ c2d,
                                                     const int* __restrict__ flaglist,
                                                     const int* __restrict__ cnt,
                                                     float* __restrict__ out_idx) {
    __shared__ double xs[DDIM];
    __shared__ double redd[256];
    __shared__ int    redi[256];
    const int tid = threadIdx.x;
    const int n = min(cnt[0], FLAGCAP);

    for (int fi = blockIdx.x; fi < n; fi += gridDim.x) {
        const int row = flaglist[fi];
        const double xv = (double)x[(size_t)row * DDIM + tid];
        xs[tid] = xv;
        redd[tid] = xv * xv;
        __syncthreads();
        for (int off = 128; off; off >>= 1) {
            if (tid < off) redd[tid] += redd[tid + off];
            __syncthreads();
        }
        const double x2 = redd[0];
        __syncthreads();

        double d2v[4];
        #pragma unroll
        for (int j = 0; j < 4; j++) {
            const int c = tid + 256 * j;
            const float* cp = cb + (size_t)c * DDIM;
            double dot = 0.0;
            for (int d = 0; d < DDIM; d += 4) {
                F4 cv; cv.v = *reinterpret_cast<const float4*>(cp + d);
                dot += xs[d+0]*(double)cv.f[0] + xs[d+1]*(double)cv.f[1]
                     + xs[d+2]*(double)cv.f[2] + xs[d+3]*(double)cv.f[3];
            }
            d2v[j] = x2 - 2.0 * dot + c2d[c];
        }
        double mv = fmin(fmin(d2v[0], d2v[1]), fmin(d2v[2], d2v[3]));
        redd[tid] = mv;
        __syncthreads();
        for (int off = 128; off; off >>= 1) {
            if (tid < off) redd[tid] = fmin(redd[tid], redd[tid + off]);
            __syncthreads();
        }
        const double thr = redd[0] + TIE_WINDOW;
        __syncthreads();
        int ci = 0x7fffffff;
        #pragma unroll
        for (int j = 0; j < 4; j++)
            if (d2v[j] <= thr) ci = min(ci, tid + 256 * j);
        redi[tid] = ci;
        __syncthreads();
        for (int off = 128; off; off >>= 1) {
            if (tid < off) redi[tid] = min(redi[tid], redi[tid + off]);
            __syncthreads();
        }
        if (tid == 0) out_idx[row] = (float)redi[0];
        __syncthreads();
    }
}

// ---- kernel 4: gather quantized + per-block squared-error partials ----
__global__ __launch_bounds__(256) void gather_kernel(const float* __restrict__ x,
                                                     const float* __restrict__ cb,
                                                     const float* __restrict__ out_idx,
                                                     float* __restrict__ out_q,
                                                     float* __restrict__ partial) {
    __shared__ float wsum[4];
    const int tid = threadIdx.x;
    const int row = blockIdx.x * 32 + (tid >> 3);
    const int d0  = (tid & 7) * 32;
    const int bi  = (int)out_idx[row];
    const float4* gq = reinterpret_cast<const float4*>(cb + (size_t)bi * DDIM + d0);
    const float4* gx = reinterpret_cast<const float4*>(x + (size_t)row * DDIM + d0);
    float4* go = reinterpret_cast<float4*>(out_q + (size_t)row * DDIM + d0);
    float sq = 0.f;
    #pragma unroll
    for (int j = 0; j < 8; j++) {
        F4 q, xv; q.v = gq[j]; xv.v = gx[j];
        go[j] = q.v;
        #pragma unroll
        for (int t = 0; t < 4; t++) { float d = q.f[t] - xv.f[t]; sq += d * d; }
    }
    #pragma unroll
    for (int off = 32; off; off >>= 1) sq += __shfl_down(sq, off);
    if ((tid & 63) == 0) wsum[tid >> 6] = sq;
    __syncthreads();
    if (tid == 0) partial[blockIdx.x] = wsum[0] + wsum[1] + wsum[2] + wsum[3];
}

// ---- kernel 5: loss reduction ----
__global__ __launch_bounds__(256) void loss_kernel(const float* __restrict__ partial,
                                                   float* __restrict__ out_loss) {
    __shared__ float w[4];
    float s = 0.f;
    for (int j = threadIdx.x; j < 2048; j += 256) s += partial[j];
    #pragma unroll
    for (int off = 32; off; off >>= 1) s += __shfl_down(s, off);
    if ((threadIdx.x & 63) == 0) w[threadIdx.x >> 6] = s;
    __syncthreads();
    if (threadIdx.x == 0)
        out_loss[0] = 1.25f * (w[0] + w[1] + w[2] + w[3]) / 16777216.f;
}

extern "C" void kernel_launch(void* const* d_in, const int* in_sizes, int n_in,
                              void* d_out, int out_size, void* d_ws, size_t ws_size,
                              hipStream_t stream) {
    const float* x  = (const float*)d_in[0];
    const float* cb = (const float*)d_in[1];
    float* out      = (float*)d_out;
    float* out_q    = out;                       // 16777216 floats
    float* out_loss = out + 16777216;            // 1 float
    float* out_idx  = out + 16777217;            // 65536 floats

    // codebook fragment buffers live in d_out's first 1 MB (gather rewrites it)
    unsigned short* fbh = (unsigned short*)d_out;            // 512 KB
    unsigned short* fbl = fbh + 262144;                      // 512 KB

    // workspace (~53 KB, proven-safe range)
    char* wsp = (char*)d_ws;
    float*  ws_c2f     = (float*) (wsp +     0);   //  4 KB
    double* ws_c2d     = (double*)(wsp +  4096);   //  8 KB
    float*  ws_partial = (float*) (wsp + 12288);   //  8 KB (2048 f32)
    int*    ws_flag    = (int*)   (wsp + 20480);   // 32 KB
    int*    ws_cnt     = (int*)   (wsp + 53248);   //  4 B

    c2_kernel<<<KCODES, 64, 0, stream>>>(cb, ws_c2f, ws_c2d, ws_cnt);
    prep_frags<<<256, 256, 0, stream>>>(cb, fbh, fbl);
    vqmfma<<<NROWS / 32, 256, 0, stream>>>(x, fbh, fbl, ws_c2f,
                                           out_idx, ws_flag, ws_cnt);
    refine_kernel<<<256, 256, 0, stream>>>(x, cb, ws_c2d, ws_flag, ws_cnt, out_idx);
    gather_kernel<<<NROWS / 32, 256, 0, stream>>>(x, cb, out_idx, out_q, ws_partial);
    loss_kernel<<<1, 256, 0, stream>>>(ws_partial, out_loss);
}

// Round 18
// 297.540 us; speedup vs baseline: 2.3904x; 1.4569x over previous
//
#include <hip/hip_runtime.h>

#define NROWS 65536
#define DDIM  256
#define KCODES 1024
#define MARGIN 0.05f        // bulk ambiguity threshold (>> split error + window)
#define TIE_WINDOW 8.0e-5   // proven r11/r12
#define FLAGCAP 8192

typedef __attribute__((ext_vector_type(8))) short bf16x8;
typedef __attribute__((ext_vector_type(4))) float f32x4;

union F4 { float4 v; float f[4]; };

__device__ __forceinline__ unsigned bf16rne(float f) {
    unsigned u = __float_as_uint(f);
    return (u + 0x7fffu + ((u >> 16) & 1u)) >> 16;
}
__device__ __forceinline__ float bf16tof(unsigned h) {
    return __uint_as_float(h << 16);
}

// ---- kernel 0: c2 f32 + f64, zero counter ----
__global__ __launch_bounds__(64) void c2_kernel(const float* __restrict__ cb,
                                                float* __restrict__ c2f,
                                                double* __restrict__ c2d,
                                                int* __restrict__ cnt) {
    const int c = blockIdx.x, lane = threadIdx.x;
    if (c == 0 && lane == 0) cnt[0] = 0;
    F4 v; v.v = reinterpret_cast<const float4*>(cb + (size_t)c * DDIM)[lane];
    double s = (double)v.f[0] * v.f[0] + (double)v.f[1] * v.f[1]
             + (double)v.f[2] * v.f[2] + (double)v.f[3] * v.f[3];
    #pragma unroll
    for (int off = 32; off; off >>= 1) s += __shfl_xor(s, off);
    if (lane == 0) { c2d[c] = s; c2f[c] = (float)s; }
}

// ---- kernel 1: codebook -> fragment-linear bf16 hi/lo ----
__global__ __launch_bounds__(256) void prep_frags(const float* __restrict__ cb,
                                                  unsigned short* __restrict__ fh,
                                                  unsigned short* __restrict__ fl) {
    int t = blockIdx.x * 256 + threadIdx.x;      // 0..65535
    int j0   = (t & 1) * 4;
    int lane = (t >> 1) & 63;
    int ks   = (t >> 7) & 7;
    int ntg  = t >> 10;
    int c = ntg * 16 + (lane & 15);
    int k = ks * 32 + (lane >> 4) * 8 + j0;
    F4 v; v.v = *reinterpret_cast<const float4*>(cb + (size_t)c * DDIM + k);
    unsigned h0 = bf16rne(v.f[0]), h1 = bf16rne(v.f[1]),
             h2 = bf16rne(v.f[2]), h3 = bf16rne(v.f[3]);
    unsigned l0 = bf16rne(v.f[0] - bf16tof(h0)), l1 = bf16rne(v.f[1] - bf16tof(h1)),
             l2 = bf16rne(v.f[2] - bf16tof(h2)), l3 = bf16rne(v.f[3] - bf16tof(h3));
    unsigned* ph = reinterpret_cast<unsigned*>(fh + (size_t)t * 4);
    unsigned* pl = reinterpret_cast<unsigned*>(fl + (size_t)t * 4);
    ph[0] = h0 | (h1 << 16); ph[1] = h2 | (h3 << 16);
    pl[0] = l0 | (l1 << 16); pl[1] = l2 | (l3 << 16);
}

// ---- kernel 2: MFMA bulk, 8 waves x (2rt x 2nt), 32 rows/block ----
// r17: 4 waves x (2rt x 4nt) -> 180 VGPR, 2 waves/SIMD, 60% idle
// (MfmaUtil 12% = exactly the MFMA floor; latency-bound). Narrower tile
// halves wave state (~120 VGPR) -> 4 waves/SIMD for latency hiding.
__global__ __launch_bounds__(512) void vqmfma(const float* __restrict__ x,
                                              const unsigned short* __restrict__ fbh,
                                              const unsigned short* __restrict__ fbl,
                                              const float* __restrict__ c2f,
                                              float* __restrict__ out_idx,
                                              int* __restrict__ flaglist,
                                              int* __restrict__ cnt) {
    __shared__ bf16x8 lds_ah[1024];    // [rt 2][ks 8][lane 64] -> 16 KB
    __shared__ bf16x8 lds_al[1024];    // 16 KB
    __shared__ float  lds_c2[KCODES];  // 4 KB
    __shared__ float  m_b1[256]; __shared__ float m_b2[256]; __shared__ int m_i1[256];

    const int tid  = threadIdx.x;
    const int w    = tid >> 6;          // 0..7 = code group (32 codes each/chunk)
    const int lane = tid & 63;
    const int row0 = blockIdx.x * 32;

    #pragma unroll
    for (int q = 0; q < 2; q++) lds_c2[q * 512 + tid] = c2f[q * 512 + tid];

    // stage x tile (32 rows) -> hi/lo fragments in LDS
    {
        const float4* gx = reinterpret_cast<const float4*>(x + (size_t)row0 * DDIM);
        unsigned* pah = reinterpret_cast<unsigned*>(lds_ah);
        unsigned* pal = reinterpret_cast<unsigned*>(lds_al);
        #pragma unroll
        for (int jj = 0; jj < 4; jj++) {
            int flat4 = jj * 512 + tid;
            int r = flat4 >> 6;                  // 0..31
            int k = (flat4 & 63) * 4;
            F4 v; v.v = gx[flat4];
            int rt = r >> 4, row = r & 15;
            int ks = k >> 5, gg = (k >> 3) & 3, j0 = k & 7;   // j0 in {0,4}
            int laneS = gg * 16 + row;
            int u32i = ((((rt * 8 + ks) * 64 + laneS) * 8 + j0) >> 1);
            unsigned h0 = bf16rne(v.f[0]), h1 = bf16rne(v.f[1]),
                     h2 = bf16rne(v.f[2]), h3 = bf16rne(v.f[3]);
            pah[u32i]     = h0 | (h1 << 16);
            pah[u32i + 1] = h2 | (h3 << 16);
            unsigned l0 = bf16rne(v.f[0] - bf16tof(h0)), l1 = bf16rne(v.f[1] - bf16tof(h1)),
                     l2 = bf16rne(v.f[2] - bf16tof(h2)), l3 = bf16rne(v.f[3] - bf16tof(h3));
            pal[u32i]     = l0 | (l1 << 16);
            pal[u32i + 1] = l2 | (l3 << 16);
        }
    }
    __syncthreads();

    float bestv[8], secv[8]; int besti[8];
    #pragma unroll
    for (int e = 0; e < 8; e++) { bestv[e] = 1e30f; secv[e] = 1e30f; besti[e] = 0; }

    const bf16x8* Bh = reinterpret_cast<const bf16x8*>(fbh);
    const bf16x8* Bl = reinterpret_cast<const bf16x8*>(fbl);

    for (int cc = 0; cc < KCODES; cc += 256) {
        f32x4 acc[2][2];
        #pragma unroll
        for (int rt = 0; rt < 2; rt++)
            #pragma unroll
            for (int nt = 0; nt < 2; nt++) acc[rt][nt] = (f32x4){0.f, 0.f, 0.f, 0.f};

        for (int ks = 0; ks < 8; ks++) {
            bf16x8 ah[2], al[2];
            #pragma unroll
            for (int rt = 0; rt < 2; rt++) {
                int slot = (rt * 8 + ks) * 64 + lane;
                ah[rt] = lds_ah[slot]; al[rt] = lds_al[slot];
            }
            #pragma unroll
            for (int nt = 0; nt < 2; nt++) {
                int ntg = (cc >> 4) + w * 2 + nt;
                int bslot = (ntg * 8 + ks) * 64 + lane;
                bf16x8 bh = Bh[bslot], bl = Bl[bslot];
                #pragma unroll
                for (int rt = 0; rt < 2; rt++) {
                    acc[rt][nt] = __builtin_amdgcn_mfma_f32_16x16x32_bf16(ah[rt], bh, acc[rt][nt], 0, 0, 0);
                    acc[rt][nt] = __builtin_amdgcn_mfma_f32_16x16x32_bf16(ah[rt], bl, acc[rt][nt], 0, 0, 0);
                    acc[rt][nt] = __builtin_amdgcn_mfma_f32_16x16x32_bf16(al[rt], bh, acc[rt][nt], 0, 0, 0);
                }
            }
        }
        // top-2 update: C/D layout col=lane&15, row=(lane>>4)*4+reg
        #pragma unroll
        for (int nt = 0; nt < 2; nt++) {
            int c = cc + w * 32 + nt * 16 + (lane & 15);
            float c2v = lds_c2[c];
            #pragma unroll
            for (int rt = 0; rt < 2; rt++)
                #pragma unroll
                for (int reg = 0; reg < 4; reg++) {
                    float s = __fmaf_rn(-2.f, acc[rt][nt][reg], c2v);
                    int e = rt * 4 + reg;
                    if (s < bestv[e]) { secv[e] = bestv[e]; bestv[e] = s; besti[e] = c; }
                    else if (s < secv[e]) secv[e] = s;
                }
        }
    }

    // merge across the 16 lanes sharing a row
    #pragma unroll
    for (int e = 0; e < 8; e++) {
        float b1 = bestv[e]; int i1 = besti[e]; float b2 = secv[e];
        #pragma unroll
        for (int off = 8; off; off >>= 1) {
            float o1 = __shfl_xor(b1, off, 16);
            int   oi = __shfl_xor(i1, off, 16);
            float o2 = __shfl_xor(b2, off, 16);
            if (o1 < b1 || (o1 == b1 && oi < i1)) { b2 = fminf(b1, o2); b1 = o1; i1 = oi; }
            else                                  { b2 = fminf(o1, b2); }
        }
        if ((lane & 15) == 0) {
            int rt = e >> 2, reg = e & 3;
            int rib = rt * 16 + (lane >> 4) * 4 + reg;  // row in block (0..31)
            m_b1[w * 32 + rib] = b1; m_i1[w * 32 + rib] = i1; m_b2[w * 32 + rib] = b2;
        }
    }
    __syncthreads();

    // cross-wave merge (8 disjoint code groups) + flag + idx
    if (tid < 32) {
        float b1 = m_b1[tid]; int i1 = m_i1[tid]; float b2 = m_b2[tid];
        #pragma unroll
        for (int ww = 1; ww < 8; ww++) {
            float o1 = m_b1[ww * 32 + tid]; int oi = m_i1[ww * 32 + tid];
            float o2 = m_b2[ww * 32 + tid];
            if (o1 < b1 || (o1 == b1 && oi < i1)) { b2 = fminf(b1, o2); b1 = o1; i1 = oi; }
            else                                  { b2 = fminf(o1, b2); }
        }
        out_idx[row0 + tid] = (float)i1;
        if (b2 - b1 < MARGIN) {
            int slot = atomicAdd(cnt, 1);
            if (slot < FLAGCAP) flaglist[slot] = row0 + tid;
        }
    }
}

// ---- kernel 3: exact-f64 window-argmin re-solve of flagged rows ----
__global__ __launch_bounds__(256) void refine_kernel(const float* __restrict__ x,
                                                     const float* __restrict__ cb,
                                                     const double* __restrict__ c2d,
                                                     const int* __restrict__ flaglist,
                                                     const int* __restrict__ cnt,
                                                     float* __restrict__ out_idx) {
    __shared__ double xs[DDIM];
    __shared__ double redd[256];
    __shared__ int    redi[256];
    const int tid = threadIdx.x;
    const int n = min(cnt[0], FLAGCAP);

    for (int fi = blockIdx.x; fi < n; fi += gridDim.x) {
        const int row = flaglist[fi];
        const double xv = (double)x[(size_t)row * DDIM + tid];
        xs[tid] = xv;
        redd[tid] = xv * xv;
        __syncthreads();
        for (int off = 128; off; off >>= 1) {
            if (tid < off) redd[tid] += redd[tid + off];
            __syncthreads();
        }
        const double x2 = redd[0];
        __syncthreads();

        double d2v[4];
        #pragma unroll
        for (int j = 0; j < 4; j++) {
            const int c = tid + 256 * j;
            const float* cp = cb + (size_t)c * DDIM;
            double dot = 0.0;
            for (int d = 0; d < DDIM; d += 4) {
                F4 cv; cv.v = *reinterpret_cast<const float4*>(cp + d);
                dot += xs[d+0]*(double)cv.f[0] + xs[d+1]*(double)cv.f[1]
                     + xs[d+2]*(double)cv.f[2] + xs[d+3]*(double)cv.f[3];
            }
            d2v[j] = x2 - 2.0 * dot + c2d[c];
        }
        double mv = fmin(fmin(d2v[0], d2v[1]), fmin(d2v[2], d2v[3]));
        redd[tid] = mv;
        __syncthreads();
        for (int off = 128; off; off >>= 1) {
            if (tid < off) redd[tid] = fmin(redd[tid], redd[tid + off]);
            __syncthreads();
        }
        const double thr = redd[0] + TIE_WINDOW;
        __syncthreads();
        int ci = 0x7fffffff;
        #pragma unroll
        for (int j = 0; j < 4; j++)
            if (d2v[j] <= thr) ci = min(ci, tid + 256 * j);
        redi[tid] = ci;
        __syncthreads();
        for (int off = 128; off; off >>= 1) {
            if (tid < off) redi[tid] = min(redi[tid], redi[tid + off]);
            __syncthreads();
        }
        if (tid == 0) out_idx[row] = (float)redi[0];
        __syncthreads();
    }
}

// ---- kernel 4: gather quantized + per-block squared-error partials ----
__global__ __launch_bounds__(256) void gather_kernel(const float* __restrict__ x,
                                                     const float* __restrict__ cb,
                                                     const float* __restrict__ out_idx,
                                                     float* __restrict__ out_q,
                                                     float* __restrict__ partial) {
    __shared__ float wsum[4];
    const int tid = threadIdx.x;
    const int row = blockIdx.x * 32 + (tid >> 3);
    const int d0  = (tid & 7) * 32;
    const int bi  = (int)out_idx[row];
    const float4* gq = reinterpret_cast<const float4*>(cb + (size_t)bi * DDIM + d0);
    const float4* gx = reinterpret_cast<const float4*>(x + (size_t)row * DDIM + d0);
    float4* go = reinterpret_cast<float4*>(out_q + (size_t)row * DDIM + d0);
    float sq = 0.f;
    #pragma unroll
    for (int j = 0; j < 8; j++) {
        F4 q, xv; q.v = gq[j]; xv.v = gx[j];
        go[j] = q.v;
        #pragma unroll
        for (int t = 0; t < 4; t++) { float d = q.f[t] - xv.f[t]; sq += d * d; }
    }
    #pragma unroll
    for (int off = 32; off; off >>= 1) sq += __shfl_down(sq, off);
    if ((tid & 63) == 0) wsum[tid >> 6] = sq;
    __syncthreads();
    if (tid == 0) partial[blockIdx.x] = wsum[0] + wsum[1] + wsum[2] + wsum[3];
}

// ---- kernel 5: loss reduction ----
__global__ __launch_bounds__(256) void loss_kernel(const float* __restrict__ partial,
                                                   float* __restrict__ out_loss) {
    __shared__ float w[4];
    float s = 0.f;
    for (int j = threadIdx.x; j < 2048; j += 256) s += partial[j];
    #pragma unroll
    for (int off = 32; off; off >>= 1) s += __shfl_down(s, off);
    if ((threadIdx.x & 63) == 0) w[threadIdx.x >> 6] = s;
    __syncthreads();
    if (threadIdx.x == 0)
        out_loss[0] = 1.25f * (w[0] + w[1] + w[2] + w[3]) / 16777216.f;
}

extern "C" void kernel_launch(void* const* d_in, const int* in_sizes, int n_in,
                              void* d_out, int out_size, void* d_ws, size_t ws_size,
                              hipStream_t stream) {
    const float* x  = (const float*)d_in[0];
    const float* cb = (const float*)d_in[1];
    float* out      = (float*)d_out;
    float* out_q    = out;                       // 16777216 floats
    float* out_loss = out + 16777216;            // 1 float
    float* out_idx  = out + 16777217;            // 65536 floats

    // codebook fragment buffers live in d_out's first 1 MB (gather rewrites it)
    unsigned short* fbh = (unsigned short*)d_out;            // 512 KB
    unsigned short* fbl = fbh + 262144;                      // 512 KB

    // workspace (~53 KB, proven-safe range)
    char* wsp = (char*)d_ws;
    float*  ws_c2f     = (float*) (wsp +     0);   //  4 KB
    double* ws_c2d     = (double*)(wsp +  4096);   //  8 KB
    float*  ws_partial = (float*) (wsp + 12288);   //  8 KB (2048 f32)
    int*    ws_flag    = (int*)   (wsp + 20480);   // 32 KB
    int*    ws_cnt     = (int*)   (wsp + 53248);   //  4 B

    c2_kernel<<<KCODES, 64, 0, stream>>>(cb, ws_c2f, ws_c2d, ws_cnt);
    prep_frags<<<256, 256, 0, stream>>>(cb, fbh, fbl);
    vqmfma<<<NROWS / 32, 512, 0, stream>>>(x, fbh, fbl, ws_c2f,
                                           out_idx, ws_flag, ws_cnt);
    refine_kernel<<<256, 256, 0, stream>>>(x, cb, ws_c2d, ws_flag, ws_cnt, out_idx);
    gather_kernel<<<NROWS / 32, 256, 0, stream>>>(x, cb, out_idx, out_q, ws_partial);
    loss_kernel<<<1, 256, 0, stream>>>(ws_partial, out_loss);
}

// Round 19
// 250.383 us; speedup vs baseline: 2.8406x; 1.1883x over previous
//
#include <hip/hip_runtime.h>

#define NROWS 65536
#define DDIM  256
#define KCODES 1024
#define MARGIN 0.05f        // bulk ambiguity threshold (>> split error + window)
#define TIE_WINDOW 8.0e-5   // proven r11/r12
#define FLAGCAP 8192

typedef __attribute__((ext_vector_type(8))) short bf16x8;
typedef __attribute__((ext_vector_type(4))) float f32x4;

union F4 { float4 v; float f[4]; };

__device__ __forceinline__ unsigned bf16rne(float f) {
    unsigned u = __float_as_uint(f);
    return (u + 0x7fffu + ((u >> 16) & 1u)) >> 16;
}
__device__ __forceinline__ float bf16tof(unsigned h) {
    return __uint_as_float(h << 16);
}

// ---- kernel 0: c2 f32 + f64, zero counter ----
__global__ __launch_bounds__(64) void c2_kernel(const float* __restrict__ cb,
                                                float* __restrict__ c2f,
                                                double* __restrict__ c2d,
                                                int* __restrict__ cnt) {
    const int c = blockIdx.x, lane = threadIdx.x;
    if (c == 0 && lane == 0) cnt[0] = 0;
    F4 v; v.v = reinterpret_cast<const float4*>(cb + (size_t)c * DDIM)[lane];
    double s = (double)v.f[0] * v.f[0] + (double)v.f[1] * v.f[1]
             + (double)v.f[2] * v.f[2] + (double)v.f[3] * v.f[3];
    #pragma unroll
    for (int off = 32; off; off >>= 1) s += __shfl_xor(s, off);
    if (lane == 0) { c2d[c] = s; c2f[c] = (float)s; }
}

// ---- kernel 1: codebook -> fragment-linear bf16 hi/lo ----
__global__ __launch_bounds__(256) void prep_frags(const float* __restrict__ cb,
                                                  unsigned short* __restrict__ fh,
                                                  unsigned short* __restrict__ fl) {
    int t = blockIdx.x * 256 + threadIdx.x;      // 0..65535
    int j0   = (t & 1) * 4;
    int lane = (t >> 1) & 63;
    int ks   = (t >> 7) & 7;
    int ntg  = t >> 10;
    int c = ntg * 16 + (lane & 15);
    int k = ks * 32 + (lane >> 4) * 8 + j0;
    F4 v; v.v = *reinterpret_cast<const float4*>(cb + (size_t)c * DDIM + k);
    unsigned h0 = bf16rne(v.f[0]), h1 = bf16rne(v.f[1]),
             h2 = bf16rne(v.f[2]), h3 = bf16rne(v.f[3]);
    unsigned l0 = bf16rne(v.f[0] - bf16tof(h0)), l1 = bf16rne(v.f[1] - bf16tof(h1)),
             l2 = bf16rne(v.f[2] - bf16tof(h2)), l3 = bf16rne(v.f[3] - bf16tof(h3));
    unsigned* ph = reinterpret_cast<unsigned*>(fh + (size_t)t * 4);
    unsigned* pl = reinterpret_cast<unsigned*>(fl + (size_t)t * 4);
    ph[0] = h0 | (h1 << 16); ph[1] = h2 | (h3 << 16);
    pl[0] = l0 | (l1 << 16); pl[1] = l2 | (l3 << 16);
}

// ---- kernel 2: MFMA bulk, 8 waves x (2rt x 2nt), 32 rows/block ----
// r19: ks loop fully unrolled + B pointers hoisted -> address VALU collapses
// to immediates, loads pipeline across ks. No min-waves clamp (r14-r16 law).
__global__ __launch_bounds__(512) void vqmfma(const float* __restrict__ x,
                                              const unsigned short* __restrict__ fbh,
                                              const unsigned short* __restrict__ fbl,
                                              const float* __restrict__ c2f,
                                              float* __restrict__ out_idx,
                                              int* __restrict__ flaglist,
                                              int* __restrict__ cnt) {
    __shared__ bf16x8 lds_ah[1024];    // [rt 2][ks 8][lane 64] -> 16 KB
    __shared__ bf16x8 lds_al[1024];    // 16 KB
    __shared__ float  lds_c2[KCODES];  // 4 KB
    __shared__ float  m_b1[256]; __shared__ float m_b2[256]; __shared__ int m_i1[256];

    const int tid  = threadIdx.x;
    const int w    = tid >> 6;          // 0..7 = code group (32 codes each/chunk)
    const int lane = tid & 63;
    const int row0 = blockIdx.x * 32;

    #pragma unroll
    for (int q = 0; q < 2; q++) lds_c2[q * 512 + tid] = c2f[q * 512 + tid];

    // stage x tile (32 rows) -> hi/lo fragments in LDS
    {
        const float4* gx = reinterpret_cast<const float4*>(x + (size_t)row0 * DDIM);
        unsigned* pah = reinterpret_cast<unsigned*>(lds_ah);
        unsigned* pal = reinterpret_cast<unsigned*>(lds_al);
        #pragma unroll
        for (int jj = 0; jj < 4; jj++) {
            int flat4 = jj * 512 + tid;
            int r = flat4 >> 6;                  // 0..31
            int k = (flat4 & 63) * 4;
            F4 v; v.v = gx[flat4];
            int rt = r >> 4, row = r & 15;
            int ks = k >> 5, gg = (k >> 3) & 3, j0 = k & 7;   // j0 in {0,4}
            int laneS = gg * 16 + row;
            int u32i = ((((rt * 8 + ks) * 64 + laneS) * 8 + j0) >> 1);
            unsigned h0 = bf16rne(v.f[0]), h1 = bf16rne(v.f[1]),
                     h2 = bf16rne(v.f[2]), h3 = bf16rne(v.f[3]);
            pah[u32i]     = h0 | (h1 << 16);
            pah[u32i + 1] = h2 | (h3 << 16);
            unsigned l0 = bf16rne(v.f[0] - bf16tof(h0)), l1 = bf16rne(v.f[1] - bf16tof(h1)),
                     l2 = bf16rne(v.f[2] - bf16tof(h2)), l3 = bf16rne(v.f[3] - bf16tof(h3));
            pal[u32i]     = l0 | (l1 << 16);
            pal[u32i + 1] = l2 | (l3 << 16);
        }
    }
    __syncthreads();

    float bestv[8], secv[8]; int besti[8];
    #pragma unroll
    for (int e = 0; e < 8; e++) { bestv[e] = 1e30f; secv[e] = 1e30f; besti[e] = 0; }

    const bf16x8* Bh = reinterpret_cast<const bf16x8*>(fbh);
    const bf16x8* Bl = reinterpret_cast<const bf16x8*>(fbl);

    for (int cc = 0; cc < KCODES; cc += 256) {
        f32x4 acc[2][2];
        #pragma unroll
        for (int rt = 0; rt < 2; rt++)
            #pragma unroll
            for (int nt = 0; nt < 2; nt++) acc[rt][nt] = (f32x4){0.f, 0.f, 0.f, 0.f};

        // hoisted per-nt fragment pointers (ks offset becomes immediate)
        const int ntg0 = (cc >> 4) + w * 2;
        const bf16x8* b0h = Bh + (size_t)(ntg0 * 8) * 64 + lane;
        const bf16x8* b0l = Bl + (size_t)(ntg0 * 8) * 64 + lane;
        const bf16x8* b1h = b0h + 8 * 64;
        const bf16x8* b1l = b0l + 8 * 64;
        const bf16x8* a0  = &lds_ah[lane];
        const bf16x8* a1  = &lds_ah[8 * 64 + lane];
        const bf16x8* a0l = &lds_al[lane];
        const bf16x8* a1l = &lds_al[8 * 64 + lane];

        #pragma unroll
        for (int ks = 0; ks < 8; ks++) {
            bf16x8 ah0 = a0[ks * 64],  ah1 = a1[ks * 64];
            bf16x8 al0 = a0l[ks * 64], al1 = a1l[ks * 64];
            bf16x8 bh0 = b0h[ks * 64], bl0 = b0l[ks * 64];
            bf16x8 bh1 = b1h[ks * 64], bl1 = b1l[ks * 64];
            acc[0][0] = __builtin_amdgcn_mfma_f32_16x16x32_bf16(ah0, bh0, acc[0][0], 0, 0, 0);
            acc[1][0] = __builtin_amdgcn_mfma_f32_16x16x32_bf16(ah1, bh0, acc[1][0], 0, 0, 0);
            acc[0][1] = __builtin_amdgcn_mfma_f32_16x16x32_bf16(ah0, bh1, acc[0][1], 0, 0, 0);
            acc[1][1] = __builtin_amdgcn_mfma_f32_16x16x32_bf16(ah1, bh1, acc[1][1], 0, 0, 0);
            acc[0][0] = __builtin_amdgcn_mfma_f32_16x16x32_bf16(ah0, bl0, acc[0][0], 0, 0, 0);
            acc[1][0] = __builtin_amdgcn_mfma_f32_16x16x32_bf16(ah1, bl0, acc[1][0], 0, 0, 0);
            acc[0][1] = __builtin_amdgcn_mfma_f32_16x16x32_bf16(ah0, bl1, acc[0][1], 0, 0, 0);
            acc[1][1] = __builtin_amdgcn_mfma_f32_16x16x32_bf16(ah1, bl1, acc[1][1], 0, 0, 0);
            acc[0][0] = __builtin_amdgcn_mfma_f32_16x16x32_bf16(al0, bh0, acc[0][0], 0, 0, 0);
            acc[1][0] = __builtin_amdgcn_mfma_f32_16x16x32_bf16(al1, bh0, acc[1][0], 0, 0, 0);
            acc[0][1] = __builtin_amdgcn_mfma_f32_16x16x32_bf16(al0, bh1, acc[0][1], 0, 0, 0);
            acc[1][1] = __builtin_amdgcn_mfma_f32_16x16x32_bf16(al1, bh1, acc[1][1], 0, 0, 0);
        }
        // top-2 update: C/D layout col=lane&15, row=(lane>>4)*4+reg
        #pragma unroll
        for (int nt = 0; nt < 2; nt++) {
            int c = cc + w * 32 + nt * 16 + (lane & 15);
            float c2v = lds_c2[c];
            #pragma unroll
            for (int rt = 0; rt < 2; rt++)
                #pragma unroll
                for (int reg = 0; reg < 4; reg++) {
                    float s = __fmaf_rn(-2.f, acc[rt][nt][reg], c2v);
                    int e = rt * 4 + reg;
                    if (s < bestv[e]) { secv[e] = bestv[e]; bestv[e] = s; besti[e] = c; }
                    else if (s < secv[e]) secv[e] = s;
                }
        }
    }

    // merge across the 16 lanes sharing a row
    #pragma unroll
    for (int e = 0; e < 8; e++) {
        float b1 = bestv[e]; int i1 = besti[e]; float b2 = secv[e];
        #pragma unroll
        for (int off = 8; off; off >>= 1) {
            float o1 = __shfl_xor(b1, off, 16);
            int   oi = __shfl_xor(i1, off, 16);
            float o2 = __shfl_xor(b2, off, 16);
            if (o1 < b1 || (o1 == b1 && oi < i1)) { b2 = fminf(b1, o2); b1 = o1; i1 = oi; }
            else                                  { b2 = fminf(o1, b2); }
        }
        if ((lane & 15) == 0) {
            int rt = e >> 2, reg = e & 3;
            int rib = rt * 16 + (lane >> 4) * 4 + reg;  // row in block (0..31)
            m_b1[w * 32 + rib] = b1; m_i1[w * 32 + rib] = i1; m_b2[w * 32 + rib] = b2;
        }
    }
    __syncthreads();

    // cross-wave merge (8 disjoint code groups) + flag + idx
    if (tid < 32) {
        float b1 = m_b1[tid]; int i1 = m_i1[tid]; float b2 = m_b2[tid];
        #pragma unroll
        for (int ww = 1; ww < 8; ww++) {
            float o1 = m_b1[ww * 32 + tid]; int oi = m_i1[ww * 32 + tid];
            float o2 = m_b2[ww * 32 + tid];
            if (o1 < b1 || (o1 == b1 && oi < i1)) { b2 = fminf(b1, o2); b1 = o1; i1 = oi; }
            else                                  { b2 = fminf(o1, b2); }
        }
        out_idx[row0 + tid] = (float)i1;
        if (b2 - b1 < MARGIN) {
            int slot = atomicAdd(cnt, 1);
            if (slot < FLAGCAP) flaglist[slot] = row0 + tid;
        }
    }
}

// ---- kernel 3: exact-f64 window-argmin re-solve of flagged rows ----
__global__ __launch_bounds__(256) void refine_kernel(const float* __restrict__ x,
                                                     const float* __restrict__ cb,
                                                     const double* __restrict__ c2d,
                                                     const int* __restrict__ flaglist,
                                                     const int* __restrict__ cnt,
                                                     float* __restrict__ out_idx) {
    __shared__ double xs[DDIM];
    __shared__ double redd[256];
    __shared__ int    redi[256];
    const int tid = threadIdx.x;
    const int n = min(cnt[0], FLAGCAP);

    for (int fi = blockIdx.x; fi < n; fi += gridDim.x) {
        const int row = flaglist[fi];
        const double xv = (double)x[(size_t)row * DDIM + tid];
        xs[tid] = xv;
        redd[tid] = xv * xv;
        __syncthreads();
        for (int off = 128; off; off >>= 1) {
            if (tid < off) redd[tid] += redd[tid + off];
            __syncthreads();
        }
        const double x2 = redd[0];
        __syncthreads();

        double d2v[4];
        #pragma unroll
        for (int j = 0; j < 4; j++) {
            const int c = tid + 256 * j;
            const float* cp = cb + (size_t)c * DDIM;
            double dot = 0.0;
            for (int d = 0; d < DDIM; d += 4) {
                F4 cv; cv.v = *reinterpret_cast<const float4*>(cp + d);
                dot += xs[d+0]*(double)cv.f[0] + xs[d+1]*(double)cv.f[1]
                     + xs[d+2]*(double)cv.f[2] + xs[d+3]*(double)cv.f[3];
            }
            d2v[j] = x2 - 2.0 * dot + c2d[c];
        }
        double mv = fmin(fmin(d2v[0], d2v[1]), fmin(d2v[2], d2v[3]));
        redd[tid] = mv;
        __syncthreads();
        for (int off = 128; off; off >>= 1) {
            if (tid < off) redd[tid] = fmin(redd[tid], redd[tid + off]);
            __syncthreads();
        }
        const double thr = redd[0] + TIE_WINDOW;
        __syncthreads();
        int ci = 0x7fffffff;
        #pragma unroll
        for (int j = 0; j < 4; j++)
            if (d2v[j] <= thr) ci = min(ci, tid + 256 * j);
        redi[tid] = ci;
        __syncthreads();
        for (int off = 128; off; off >>= 1) {
            if (tid < off) redi[tid] = min(redi[tid], redi[tid + off]);
            __syncthreads();
        }
        if (tid == 0) out_idx[row] = (float)redi[0];
        __syncthreads();
    }
}

// ---- kernel 4: gather quantized + per-block squared-error partials ----
__global__ __launch_bounds__(256) void gather_kernel(const float* __restrict__ x,
                                                     const float* __restrict__ cb,
                                                     const float* __restrict__ out_idx,
                                                     float* __restrict__ out_q,
                                                     float* __restrict__ partial) {
    __shared__ float wsum[4];
    const int tid = threadIdx.x;
    const int row = blockIdx.x * 32 + (tid >> 3);
    const int d0  = (tid & 7) * 32;
    const int bi  = (int)out_idx[row];
    const float4* gq = reinterpret_cast<const float4*>(cb + (size_t)bi * DDIM + d0);
    const float4* gx = reinterpret_cast<const float4*>(x + (size_t)row * DDIM + d0);
    float4* go = reinterpret_cast<float4*>(out_q + (size_t)row * DDIM + d0);
    float sq = 0.f;
    #pragma unroll
    for (int j = 0; j < 8; j++) {
        F4 q, xv; q.v = gq[j]; xv.v = gx[j];
        go[j] = q.v;
        #pragma unroll
        for (int t = 0; t < 4; t++) { float d = q.f[t] - xv.f[t]; sq += d * d; }
    }
    #pragma unroll
    for (int off = 32; off; off >>= 1) sq += __shfl_down(sq, off);
    if ((tid & 63) == 0) wsum[tid >> 6] = sq;
    __syncthreads();
    if (tid == 0) partial[blockIdx.x] = wsum[0] + wsum[1] + wsum[2] + wsum[3];
}

// ---- kernel 5: loss reduction ----
__global__ __launch_bounds__(256) void loss_kernel(const float* __restrict__ partial,
                                                   float* __restrict__ out_loss) {
    __shared__ float w[4];
    float s = 0.f;
    for (int j = threadIdx.x; j < 2048; j += 256) s += partial[j];
    #pragma unroll
    for (int off = 32; off; off >>= 1) s += __shfl_down(s, off);
    if ((threadIdx.x & 63) == 0) w[threadIdx.x >> 6] = s;
    __syncthreads();
    if (threadIdx.x == 0)
        out_loss[0] = 1.25f * (w[0] + w[1] + w[2] + w[3]) / 16777216.f;
}

extern "C" void kernel_launch(void* const* d_in, const int* in_sizes, int n_in,
                              void* d_out, int out_size, void* d_ws, size_t ws_size,
                              hipStream_t stream) {
    const float* x  = (const float*)d_in[0];
    const float* cb = (const float*)d_in[1];
    float* out      = (float*)d_out;
    float* out_q    = out;                       // 16777216 floats
    float* out_loss = out + 16777216;            // 1 float
    float* out_idx  = out + 16777217;            // 65536 floats

    // codebook fragment buffers live in d_out's first 1 MB (gather rewrites it)
    unsigned short* fbh = (unsigned short*)d_out;            // 512 KB
    unsigned short* fbl = fbh + 262144;                      // 512 KB

    // workspace (~53 KB, proven-safe range)
    char* wsp = (char*)d_ws;
    float*  ws_c2f     = (float*) (wsp +     0);   //  4 KB
    double* ws_c2d     = (double*)(wsp +  4096);   //  8 KB
    float*  ws_partial = (float*) (wsp + 12288);   //  8 KB (2048 f32)
    int*    ws_flag    = (int*)   (wsp + 20480);   // 32 KB
    int*    ws_cnt     = (int*)   (wsp + 53248);   //  4 B

    c2_kernel<<<KCODES, 64, 0, stream>>>(cb, ws_c2f, ws_c2d, ws_cnt);
    prep_frags<<<256, 256, 0, stream>>>(cb, fbh, fbl);
    vqmfma<<<NROWS / 32, 512, 0, stream>>>(x, fbh, fbl, ws_c2f,
                                           out_idx, ws_flag, ws_cnt);
    refine_kernel<<<256, 256, 0, stream>>>(x, cb, ws_c2d, ws_flag, ws_cnt, out_idx);
    gather_kernel<<<NROWS / 32, 256, 0, stream>>>(x, cb, out_idx, out_q, ws_partial);
    loss_kernel<<<1, 256, 0, stream>>>(ws_partial, out_loss);
}